// Round 1
// baseline (990.377 us; speedup 1.0000x reference)
//
#include <hip/hip_runtime.h>
#include <hip/hip_bf16.h>

typedef __attribute__((ext_vector_type(8))) __bf16 bf16x8;
typedef __attribute__((ext_vector_type(4))) __bf16 bf16x4;
typedef __attribute__((ext_vector_type(4))) float f32x4;

#define T_TOK 2048
#define NH 32
#define NKV 4
#define HD 128
#define HID 2048
#define QKV_N 5120   // (32 + 2*4) * 128
#define QSZ 4096     // 32*128
#define KOFF 4096
#define VOFF 4608
#define ATT_N 4096

// ---------------- cast fp32 -> bf16 (row-major, vectorized) ----------------
__global__ __launch_bounds__(256) void cast_f32_bf16(const float* __restrict__ in,
                                                     __bf16* __restrict__ out, int n4) {
  int i = blockIdx.x * 256 + threadIdx.x;
  if (i < n4) {
    float4 v = reinterpret_cast<const float4*>(in)[i];
    bf16x4 o;
    o[0] = (__bf16)v.x; o[1] = (__bf16)v.y; o[2] = (__bf16)v.z; o[3] = (__bf16)v.w;
    reinterpret_cast<bf16x4*>(out)[i] = o;
  }
}

// ------------- cast + transpose: in fp32 [R][C] -> out bf16 [C][R] ---------
__global__ __launch_bounds__(256) void transpose_cast(const float* __restrict__ in,
                                                      __bf16* __restrict__ out,
                                                      int R, int C) {
  __shared__ float tile[64][65];
  int c0 = blockIdx.x * 64;
  int r0 = blockIdx.y * 64;
  int tx = threadIdx.x & 63;
  int ty = threadIdx.x >> 6;  // 0..3
#pragma unroll
  for (int i = 0; i < 64; i += 4)
    tile[ty + i][tx] = in[(size_t)(r0 + ty + i) * C + c0 + tx];
  __syncthreads();
#pragma unroll
  for (int i = 0; i < 64; i += 4)
    out[(size_t)(c0 + ty + i) * R + r0 + tx] = (__bf16)tile[tx][ty + i];
}

// ---------------- GEMM: C[M][N] = A[M][K] * B^T  (B stored [N][K]) ----------
// 128x128 tile, BK=32, 4 waves (2x2), each wave 64x64 via 4x4 16x16x32 MFMAs.
template <int OUTF32>
__global__ __launch_bounds__(256) void gemm_bt(const __bf16* __restrict__ A,
                                               const __bf16* __restrict__ B,
                                               void* __restrict__ Cp,
                                               int M, int N, int K) {
  __shared__ __attribute__((aligned(16))) __bf16 As[128][40];
  __shared__ __attribute__((aligned(16))) __bf16 Bs[128][40];
  const int tid = threadIdx.x;
  const int lane = tid & 63;
  const int wave = tid >> 6;
  const int la = lane & 15;
  const int lb = lane >> 4;
  const int wr = (wave >> 1) * 64;
  const int wc = (wave & 1) * 64;
  const int rowA0 = blockIdx.y * 128;
  const int rowB0 = blockIdx.x * 128;

  f32x4 acc[4][4] = {};

  const int r_st = tid >> 2;        // 0..63
  const int c_st = (tid & 3) * 8;   // 0,8,16,24

  for (int k0 = 0; k0 < K; k0 += 32) {
    bf16x8 a0 = *reinterpret_cast<const bf16x8*>(&A[(size_t)(rowA0 + r_st) * K + k0 + c_st]);
    bf16x8 a1 = *reinterpret_cast<const bf16x8*>(&A[(size_t)(rowA0 + 64 + r_st) * K + k0 + c_st]);
    bf16x8 b0 = *reinterpret_cast<const bf16x8*>(&B[(size_t)(rowB0 + r_st) * K + k0 + c_st]);
    bf16x8 b1 = *reinterpret_cast<const bf16x8*>(&B[(size_t)(rowB0 + 64 + r_st) * K + k0 + c_st]);
    *reinterpret_cast<bf16x8*>(&As[r_st][c_st]) = a0;
    *reinterpret_cast<bf16x8*>(&As[64 + r_st][c_st]) = a1;
    *reinterpret_cast<bf16x8*>(&Bs[r_st][c_st]) = b0;
    *reinterpret_cast<bf16x8*>(&Bs[64 + r_st][c_st]) = b1;
    __syncthreads();
    bf16x8 af[4], bfr[4];
#pragma unroll
    for (int m = 0; m < 4; ++m)
      af[m] = *reinterpret_cast<const bf16x8*>(&As[wr + m * 16 + la][lb * 8]);
#pragma unroll
    for (int n = 0; n < 4; ++n)
      bfr[n] = *reinterpret_cast<const bf16x8*>(&Bs[wc + n * 16 + la][lb * 8]);
#pragma unroll
    for (int m = 0; m < 4; ++m)
#pragma unroll
      for (int n = 0; n < 4; ++n)
        acc[m][n] = __builtin_amdgcn_mfma_f32_16x16x32_bf16(af[m], bfr[n], acc[m][n], 0, 0, 0);
    __syncthreads();
  }

#pragma unroll
  for (int m = 0; m < 4; ++m) {
#pragma unroll
    for (int n = 0; n < 4; ++n) {
#pragma unroll
      for (int r = 0; r < 4; ++r) {
        int row = rowA0 + wr + m * 16 + lb * 4 + r;
        int col = rowB0 + wc + n * 16 + la;
        if (OUTF32)
          reinterpret_cast<float*>(Cp)[(size_t)row * N + col] = acc[m][n][r];
        else
          reinterpret_cast<__bf16*>(Cp)[(size_t)row * N + col] = (__bf16)acc[m][n][r];
      }
    }
  }
}

// ------------- RMSNorm + RoPE in-place on q/k rows of qkv buffer -----------
__global__ __launch_bounds__(128) void norm_rope(__bf16* __restrict__ qkv,
                                                 const int* __restrict__ positions,
                                                 const float* __restrict__ qw,
                                                 const float* __restrict__ kw) {
  const int t = blockIdx.x;
  const int head = blockIdx.y;  // 0..35: 0-31 q heads, 32-35 k heads
  const bool is_q = head < NH;
  const int col = is_q ? head * HD : KOFF + (head - NH) * HD;
  __bf16* row = qkv + (size_t)t * QKV_N + col;
  const int d = threadIdx.x;  // 0..127
  float x = (float)row[d];
  float ss = x * x;
#pragma unroll
  for (int mm = 1; mm < 64; mm <<= 1) ss += __shfl_xor(ss, mm);
  __shared__ float red[2];
  __shared__ float yl[128];
  if ((d & 63) == 0) red[d >> 6] = ss;
  __syncthreads();
  float var = (red[0] + red[1]) * (1.0f / 128.0f);
  float sc = rsqrtf(var + 1e-6f);
  const float* wv = is_q ? qw : kw;
  yl[d] = x * sc * wv[d];
  __syncthreads();
  if (d < 64) {
    float x1 = yl[d], x2 = yl[d + 64];
    float fr = (float)positions[t] * powf(10000.0f, -(float)d / 64.0f);
    float c, sn;
    sincosf(fr, &sn, &c);
    row[d] = (__bf16)(x1 * c - x2 * sn);
    row[d + 64] = (__bf16)(x2 * c + x1 * sn);
  }
}

// ---------------- causal GQA flash attention, 1 wave / 16 q-rows -----------
__global__ __launch_bounds__(64) void flash_attn(const __bf16* __restrict__ qkv,
                                                 __bf16* __restrict__ attn) {
  const int h = blockIdx.y;
  const int qbase = blockIdx.x * 16;
  const int hkv = h >> 3;  // H/HKV = 8
  const int lane = threadIdx.x;
  const int la = lane & 15;
  const int lb = lane >> 4;

  const __bf16* Qp = qkv + (size_t)(qbase + la) * QKV_N + h * HD;
  const __bf16* Kp = qkv + KOFF + hkv * HD;
  const __bf16* Vp = qkv + VOFF + hkv * HD;

  bf16x8 qf[4];
#pragma unroll
  for (int kk = 0; kk < 4; ++kk)
    qf[kk] = *reinterpret_cast<const bf16x8*>(Qp + kk * 32 + lb * 8);

  f32x4 acc[8] = {};
  float mrow[4], lrow[4];
#pragma unroll
  for (int r = 0; r < 4; ++r) { mrow[r] = -1e30f; lrow[r] = 0.0f; }

  __shared__ __attribute__((aligned(16))) __bf16 pl[16][40];
  __shared__ __attribute__((aligned(16))) __bf16 vt[128][40];

  const float scale = 0.088388347648318447f;  // 1/sqrt(128)

  for (int kv0 = 0; kv0 < qbase + 16; kv0 += 32) {
    // stage V^T into LDS: vt[d][kv]
#pragma unroll
    for (int it = 0; it < 8; ++it) {
      int c = it * 64 + lane;
      int r = c >> 4;            // 0..31 kv row
      int c8 = (c & 15) * 8;     // d chunk
      bf16x8 v = *reinterpret_cast<const bf16x8*>(&Vp[(size_t)(kv0 + r) * QKV_N + c8]);
#pragma unroll
      for (int j = 0; j < 8; ++j) vt[c8 + j][r] = v[j];
    }
    // QK^T: S[16 q][32 kv]
    f32x4 st[2] = {};
#pragma unroll
    for (int n = 0; n < 2; ++n)
#pragma unroll
      for (int kk = 0; kk < 4; ++kk) {
        bf16x8 kf = *reinterpret_cast<const bf16x8*>(
            &Kp[(size_t)(kv0 + n * 16 + la) * QKV_N + kk * 32 + lb * 8]);
        st[n] = __builtin_amdgcn_mfma_f32_16x16x32_bf16(qf[kk], kf, st[n], 0, 0, 0);
      }
    // online softmax; write P to LDS
#pragma unroll
    for (int r = 0; r < 4; ++r) {
      const int row = qbase + lb * 4 + r;
      float s0 = (kv0 + la <= row) ? st[0][r] * scale : -1e30f;
      float s1 = (kv0 + 16 + la <= row) ? st[1][r] * scale : -1e30f;
      float mx = fmaxf(s0, s1);
#pragma unroll
      for (int mm = 1; mm < 16; mm <<= 1) mx = fmaxf(mx, __shfl_xor(mx, mm));
      float mnew = fmaxf(mrow[r], mx);
      float p0 = __expf(s0 - mnew);
      float p1 = __expf(s1 - mnew);
      float corr = __expf(mrow[r] - mnew);
      float ps = p0 + p1;
#pragma unroll
      for (int mm = 1; mm < 16; mm <<= 1) ps += __shfl_xor(ps, mm);
      lrow[r] = lrow[r] * corr + ps;
      mrow[r] = mnew;
#pragma unroll
      for (int dt = 0; dt < 8; ++dt) acc[dt][r] *= corr;
      pl[lb * 4 + r][la] = (__bf16)p0;
      pl[lb * 4 + r][16 + la] = (__bf16)p1;
    }
    __syncthreads();
    // PV: out[16 q][128 d] += P[16 q][32 kv] * V[32 kv][128 d]
    bf16x8 pa = *reinterpret_cast<const bf16x8*>(&pl[la][lb * 8]);
#pragma unroll
    for (int dt = 0; dt < 8; ++dt) {
      bf16x8 vb = *reinterpret_cast<const bf16x8*>(&vt[dt * 16 + la][lb * 8]);
      acc[dt] = __builtin_amdgcn_mfma_f32_16x16x32_bf16(pa, vb, acc[dt], 0, 0, 0);
    }
    __syncthreads();
  }
  // epilogue
#pragma unroll
  for (int dt = 0; dt < 8; ++dt) {
#pragma unroll
    for (int r = 0; r < 4; ++r) {
      int row = qbase + lb * 4 + r;
      int col = h * HD + dt * 16 + la;
      attn[(size_t)row * ATT_N + col] = (__bf16)(acc[dt][r] / lrow[r]);
    }
  }
}

extern "C" void kernel_launch(void* const* d_in, const int* in_sizes, int n_in,
                              void* d_out, int out_size, void* d_ws, size_t ws_size,
                              hipStream_t stream) {
  const float* hs   = (const float*)d_in[0];
  const int*   pos  = (const int*)d_in[1];
  const float* wqkv = (const float*)d_in[2];
  const float* wo   = (const float*)d_in[3];
  const float* qw   = (const float*)d_in[4];
  const float* kw   = (const float*)d_in[5];
  float* out = (float*)d_out;

  char* p = (char*)d_ws;
  __bf16* hsb   = (__bf16*)p; p += (size_t)T_TOK * HID * 2;    // 8.4 MB
  __bf16* wqkvT = (__bf16*)p; p += (size_t)QKV_N * HID * 2;    // 21 MB  [5120][2048]
  __bf16* woT   = (__bf16*)p; p += (size_t)HID * QSZ * 2;      // 16.8 MB [2048][4096]
  __bf16* qkvb  = (__bf16*)p; p += (size_t)T_TOK * QKV_N * 2;  // 21 MB
  __bf16* attnb = (__bf16*)p; p += (size_t)T_TOK * QSZ * 2;    // 16.8 MB

  // 1. casts / transposes
  cast_f32_bf16<<<(T_TOK * HID / 4) / 256, 256, 0, stream>>>(hs, hsb, T_TOK * HID / 4);
  transpose_cast<<<dim3(QKV_N / 64, HID / 64), 256, 0, stream>>>(wqkv, wqkvT, HID, QKV_N);
  transpose_cast<<<dim3(HID / 64, QSZ / 64), 256, 0, stream>>>(wo, woT, QSZ, HID);
  // 2. QKV projection: [2048][5120] = [2048][2048] x [5120][2048]^T
  gemm_bt<0><<<dim3(QKV_N / 128, T_TOK / 128), 256, 0, stream>>>(hsb, wqkvT, qkvb,
                                                                 T_TOK, QKV_N, HID);
  // 3. RMSNorm + RoPE in place on q,k
  norm_rope<<<dim3(T_TOK, NH + NKV), 128, 0, stream>>>(qkvb, pos, qw, kw);
  // 4. causal GQA flash attention
  flash_attn<<<dim3(T_TOK / 16, NH), 64, 0, stream>>>(qkvb, attnb);
  // 5. output projection: [2048][2048] = [2048][4096] x [2048][4096]^T
  gemm_bt<1><<<dim3(HID / 128, T_TOK / 128), 256, 0, stream>>>(attnb, woT, out,
                                                               T_TOK, HID, QSZ);
}

// Round 2
// 385.549 us; speedup vs baseline: 2.5687x; 2.5687x over previous
//
#include <hip/hip_runtime.h>
#include <hip/hip_bf16.h>

typedef __attribute__((ext_vector_type(8))) __bf16 bf16x8;
typedef __attribute__((ext_vector_type(4))) __bf16 bf16x4;
typedef __attribute__((ext_vector_type(4))) float f32x4;

#define T_TOK 2048
#define NH 32
#define NKV 4
#define HD 128
#define HID 2048
#define QKV_N 5120   // (32 + 2*4) * 128
#define QSZ 4096     // 32*128
#define KOFF 4096
#define VOFF 4608
#define ATT_N 4096

// ---------------- cast fp32 -> bf16 (row-major, vectorized) ----------------
__global__ __launch_bounds__(256) void cast_f32_bf16(const float* __restrict__ in,
                                                     __bf16* __restrict__ out, int n4) {
  int i = blockIdx.x * 256 + threadIdx.x;
  if (i < n4) {
    float4 v = reinterpret_cast<const float4*>(in)[i];
    bf16x4 o;
    o[0] = (__bf16)v.x; o[1] = (__bf16)v.y; o[2] = (__bf16)v.z; o[3] = (__bf16)v.w;
    reinterpret_cast<bf16x4*>(out)[i] = o;
  }
}

// ------------- cast + transpose: in fp32 [R][C] -> out bf16 [C][R] ---------
__global__ __launch_bounds__(256) void transpose_cast(const float* __restrict__ in,
                                                      __bf16* __restrict__ out,
                                                      int R, int C) {
  __shared__ float tile[64][65];
  int c0 = blockIdx.x * 64;
  int r0 = blockIdx.y * 64;
  int tx = threadIdx.x & 63;
  int ty = threadIdx.x >> 6;  // 0..3
#pragma unroll
  for (int i = 0; i < 64; i += 4)
    tile[ty + i][tx] = in[(size_t)(r0 + ty + i) * C + c0 + tx];
  __syncthreads();
#pragma unroll
  for (int i = 0; i < 64; i += 4)
    out[(size_t)(c0 + ty + i) * R + r0 + tx] = (__bf16)tile[tx][ty + i];
}

// ---- transpose V section of qkv: [t][kvh*128+d] -> vt[kvh][d][t] (bf16) ----
__global__ __launch_bounds__(256) void v_transpose(const __bf16* __restrict__ qkv,
                                                   __bf16* __restrict__ vt) {
  __shared__ __bf16 tile[64][72];
  int t0 = blockIdx.x * 64;
  int d0 = blockIdx.y * 64;
  int kvh = blockIdx.z;
  int tx = threadIdx.x & 63;
  int ty = threadIdx.x >> 6;
#pragma unroll
  for (int i = 0; i < 64; i += 4)
    tile[ty + i][tx] = qkv[(size_t)(t0 + ty + i) * QKV_N + VOFF + kvh * HD + d0 + tx];
  __syncthreads();
#pragma unroll
  for (int i = 0; i < 64; i += 4)
    vt[((size_t)kvh * HD + d0 + ty + i) * T_TOK + t0 + tx] = tile[tx][ty + i];
}

// ---------------- GEMM: C[M][N] = A[M][K] * B^T  (B stored [N][K]) ----------
template <int OUTF32>
__global__ __launch_bounds__(256) void gemm_bt(const __bf16* __restrict__ A,
                                               const __bf16* __restrict__ B,
                                               void* __restrict__ Cp,
                                               int M, int N, int K) {
  __shared__ __attribute__((aligned(16))) __bf16 As[128][40];
  __shared__ __attribute__((aligned(16))) __bf16 Bs[128][40];
  const int tid = threadIdx.x;
  const int lane = tid & 63;
  const int wave = tid >> 6;
  const int la = lane & 15;
  const int lb = lane >> 4;
  const int wr = (wave >> 1) * 64;
  const int wc = (wave & 1) * 64;
  const int rowA0 = blockIdx.y * 128;
  const int rowB0 = blockIdx.x * 128;

  f32x4 acc[4][4] = {};

  const int r_st = tid >> 2;        // 0..63
  const int c_st = (tid & 3) * 8;   // 0,8,16,24

  for (int k0 = 0; k0 < K; k0 += 32) {
    bf16x8 a0 = *reinterpret_cast<const bf16x8*>(&A[(size_t)(rowA0 + r_st) * K + k0 + c_st]);
    bf16x8 a1 = *reinterpret_cast<const bf16x8*>(&A[(size_t)(rowA0 + 64 + r_st) * K + k0 + c_st]);
    bf16x8 b0 = *reinterpret_cast<const bf16x8*>(&B[(size_t)(rowB0 + r_st) * K + k0 + c_st]);
    bf16x8 b1 = *reinterpret_cast<const bf16x8*>(&B[(size_t)(rowB0 + 64 + r_st) * K + k0 + c_st]);
    *reinterpret_cast<bf16x8*>(&As[r_st][c_st]) = a0;
    *reinterpret_cast<bf16x8*>(&As[64 + r_st][c_st]) = a1;
    *reinterpret_cast<bf16x8*>(&Bs[r_st][c_st]) = b0;
    *reinterpret_cast<bf16x8*>(&Bs[64 + r_st][c_st]) = b1;
    __syncthreads();
    bf16x8 af[4], bfr[4];
#pragma unroll
    for (int m = 0; m < 4; ++m)
      af[m] = *reinterpret_cast<const bf16x8*>(&As[wr + m * 16 + la][lb * 8]);
#pragma unroll
    for (int n = 0; n < 4; ++n)
      bfr[n] = *reinterpret_cast<const bf16x8*>(&Bs[wc + n * 16 + la][lb * 8]);
#pragma unroll
    for (int m = 0; m < 4; ++m)
#pragma unroll
      for (int n = 0; n < 4; ++n)
        acc[m][n] = __builtin_amdgcn_mfma_f32_16x16x32_bf16(af[m], bfr[n], acc[m][n], 0, 0, 0);
    __syncthreads();
  }

#pragma unroll
  for (int m = 0; m < 4; ++m) {
#pragma unroll
    for (int n = 0; n < 4; ++n) {
#pragma unroll
      for (int r = 0; r < 4; ++r) {
        int row = rowA0 + wr + m * 16 + lb * 4 + r;
        int col = rowB0 + wc + n * 16 + la;
        if (OUTF32)
          reinterpret_cast<float*>(Cp)[(size_t)row * N + col] = acc[m][n][r];
        else
          reinterpret_cast<__bf16*>(Cp)[(size_t)row * N + col] = (__bf16)acc[m][n][r];
      }
    }
  }
}

// ------------- RMSNorm + RoPE in-place on q/k rows of qkv buffer -----------
__global__ __launch_bounds__(128) void norm_rope(__bf16* __restrict__ qkv,
                                                 const int* __restrict__ positions,
                                                 const float* __restrict__ qw,
                                                 const float* __restrict__ kw) {
  const int t = blockIdx.x;
  const int head = blockIdx.y;  // 0..35: 0-31 q heads, 32-35 k heads
  const bool is_q = head < NH;
  const int col = is_q ? head * HD : KOFF + (head - NH) * HD;
  __bf16* row = qkv + (size_t)t * QKV_N + col;
  const int d = threadIdx.x;  // 0..127
  float x = (float)row[d];
  float ss = x * x;
#pragma unroll
  for (int mm = 1; mm < 64; mm <<= 1) ss += __shfl_xor(ss, mm);
  __shared__ float red[2];
  __shared__ float yl[128];
  if ((d & 63) == 0) red[d >> 6] = ss;
  __syncthreads();
  float var = (red[0] + red[1]) * (1.0f / 128.0f);
  float sc = rsqrtf(var + 1e-6f);
  const float* wv = is_q ? qw : kw;
  yl[d] = x * sc * wv[d];
  __syncthreads();
  if (d < 64) {
    float x1 = yl[d], x2 = yl[d + 64];
    float fr = (float)positions[t] * powf(10000.0f, -(float)d / 64.0f);
    float c, sn;
    sincosf(fr, &sn, &c);
    row[d] = (__bf16)(x1 * c - x2 * sn);
    row[d + 64] = (__bf16)(x2 * c + x1 * sn);
  }
}

// ------------- causal GQA flash attention, 4 waves = 4 heads / block --------
// block: 16 q-rows x 4 heads (half of one GQA group); KVBLK=64 staged in LDS.
// grid: (64 qtile-pairs, 8 = kvh*2 + head-half). Each block does qtiles
// {x, 127-x} sequentially -> uniform causal work.
#define KVB 64
#define KS_LD 152   // 128 + 24 pad: row stride 304B == 12 banks (mod 32) -> floor
#define VS_LD 88    // 64 + 24 pad
#define PL_LD 88

__global__ __launch_bounds__(256) void flash_attn2(const __bf16* __restrict__ qkv,
                                                   const __bf16* __restrict__ vt,
                                                   __bf16* __restrict__ attn) {
  __shared__ __attribute__((aligned(16))) __bf16 Ks[KVB][KS_LD];
  __shared__ __attribute__((aligned(16))) __bf16 Vs[HD][VS_LD];
  __shared__ __attribute__((aligned(16))) __bf16 pl[4][16][PL_LD];

  const int tid = threadIdx.x;
  const int lane = tid & 63;
  const int wave = tid >> 6;
  const int la = lane & 15;
  const int lb = lane >> 4;
  const int kvh = blockIdx.y >> 1;
  const int h = kvh * 8 + (blockIdx.y & 1) * 4 + wave;
  const __bf16* Kbase = qkv + KOFF + kvh * HD;
  const __bf16* Vbase = vt + (size_t)kvh * HD * T_TOK;

  // 1/sqrt(128) * log2(e): QK^T lands in log2 domain -> exp2 everywhere
  const float qscale = 0.088388347648318447f * 1.4426950408889634f;

  for (int seg = 0; seg < 2; ++seg) {
    const int qt = (seg == 0) ? (int)blockIdx.x : 127 - (int)blockIdx.x;
    const int qb = qt * 16;

    bf16x8 qf[4];
    const __bf16* Qp = qkv + (size_t)(qb + la) * QKV_N + h * HD;
#pragma unroll
    for (int kk = 0; kk < 4; ++kk) {
      bf16x8 q = *reinterpret_cast<const bf16x8*>(Qp + kk * 32 + lb * 8);
#pragma unroll
      for (int j = 0; j < 8; ++j) q[j] = (__bf16)((float)q[j] * qscale);
      qf[kk] = q;
    }

    f32x4 acc[8] = {};
    float mrow[4] = {-1e30f, -1e30f, -1e30f, -1e30f};
    float lrow[4] = {0.0f, 0.0f, 0.0f, 0.0f};

    const int kvend = qb + 16;
    for (int kv0 = 0; kv0 < kvend; kv0 += KVB) {
      __syncthreads();  // previous tile fully consumed before overwrite
      // ---- cooperative stage: K[64][128] rows, V^T[128][64] rows ----
#pragma unroll
      for (int p = 0; p < 4; ++p) {
        int g = p * 256 + tid;
        int kr = g >> 4, kc = g & 15;
        bf16x8 k8 = *reinterpret_cast<const bf16x8*>(
            &Kbase[(size_t)(kv0 + kr) * QKV_N + kc * 8]);
        *reinterpret_cast<bf16x8*>(&Ks[kr][kc * 8]) = k8;
        int vr = g >> 3, vc = g & 7;
        bf16x8 v8 = *reinterpret_cast<const bf16x8*>(
            &Vbase[(size_t)vr * T_TOK + kv0 + vc * 8]);
        *reinterpret_cast<bf16x8*>(&Vs[vr][vc * 8]) = v8;
      }
      __syncthreads();

      // ---- QK^T: S[16 q][64 kv], log2 domain ----
      f32x4 st[4] = {};
#pragma unroll
      for (int n = 0; n < 4; ++n)
#pragma unroll
        for (int kk = 0; kk < 4; ++kk) {
          bf16x8 kf = *reinterpret_cast<const bf16x8*>(&Ks[n * 16 + la][kk * 32 + lb * 8]);
          st[n] = __builtin_amdgcn_mfma_f32_16x16x32_bf16(qf[kk], kf, st[n], 0, 0, 0);
        }

      // ---- online softmax (defer-max: skip rescale when max stable) ----
      const bool fullvalid = (kv0 + KVB - 1 <= qb);  // block-uniform
      float mnew4[4];
      bool need = false;
#pragma unroll
      for (int r = 0; r < 4; ++r) {
        const int row = qb + lb * 4 + r;
        float mx = -1e30f;
#pragma unroll
        for (int n = 0; n < 4; ++n) {
          float s = st[n][r];
          if (!fullvalid && (kv0 + n * 16 + la > row)) s = -1e30f;
          st[n][r] = s;
          mx = fmaxf(mx, s);
        }
#pragma unroll
        for (int mm = 1; mm < 16; mm <<= 1) mx = fmaxf(mx, __shfl_xor(mx, mm));
        mnew4[r] = mx;
        need = need || (mx > mrow[r]);
      }
      if (__any(need)) {
#pragma unroll
        for (int r = 0; r < 4; ++r) {
          float mnew = fmaxf(mrow[r], mnew4[r]);
          float corr = exp2f(mrow[r] - mnew);
          mrow[r] = mnew;
          lrow[r] *= corr;
#pragma unroll
          for (int dt = 0; dt < 8; ++dt) acc[dt][r] *= corr;
        }
      }
#pragma unroll
      for (int r = 0; r < 4; ++r) {
        float ps = 0.0f;
#pragma unroll
        for (int n = 0; n < 4; ++n) {
          float p = exp2f(st[n][r] - mrow[r]);
          ps += p;
          pl[wave][lb * 4 + r][n * 16 + la] = (__bf16)p;
        }
#pragma unroll
        for (int mm = 1; mm < 16; mm <<= 1) ps += __shfl_xor(ps, mm);
        lrow[r] += ps;
      }

      // ---- PV: out[16 q][128 d] += P[16][64] * V[64][128] ----
#pragma unroll
      for (int ks = 0; ks < 2; ++ks) {
        bf16x8 paf = *reinterpret_cast<const bf16x8*>(&pl[wave][la][ks * 32 + lb * 8]);
#pragma unroll
        for (int dt = 0; dt < 8; ++dt) {
          bf16x8 vbf = *reinterpret_cast<const bf16x8*>(&Vs[dt * 16 + la][ks * 32 + lb * 8]);
          acc[dt] = __builtin_amdgcn_mfma_f32_16x16x32_bf16(paf, vbf, acc[dt], 0, 0, 0);
        }
      }
    }

    // ---- epilogue ----
    float inv[4];
#pragma unroll
    for (int r = 0; r < 4; ++r) inv[r] = 1.0f / lrow[r];
#pragma unroll
    for (int dt = 0; dt < 8; ++dt)
#pragma unroll
      for (int r = 0; r < 4; ++r)
        attn[(size_t)(qb + lb * 4 + r) * ATT_N + h * HD + dt * 16 + la] =
            (__bf16)(acc[dt][r] * inv[r]);
  }
}

extern "C" void kernel_launch(void* const* d_in, const int* in_sizes, int n_in,
                              void* d_out, int out_size, void* d_ws, size_t ws_size,
                              hipStream_t stream) {
  const float* hs   = (const float*)d_in[0];
  const int*   pos  = (const int*)d_in[1];
  const float* wqkv = (const float*)d_in[2];
  const float* wo   = (const float*)d_in[3];
  const float* qw   = (const float*)d_in[4];
  const float* kw   = (const float*)d_in[5];
  float* out = (float*)d_out;

  char* p = (char*)d_ws;
  __bf16* hsb   = (__bf16*)p; p += (size_t)T_TOK * HID * 2;     // 8.4 MB
  __bf16* wqkvT = (__bf16*)p; p += (size_t)QKV_N * HID * 2;     // 21 MB  [5120][2048]
  __bf16* woT   = (__bf16*)p; p += (size_t)HID * QSZ * 2;       // 16.8 MB [2048][4096]
  __bf16* qkvb  = (__bf16*)p; p += (size_t)T_TOK * QKV_N * 2;   // 21 MB
  __bf16* attnb = (__bf16*)p; p += (size_t)T_TOK * QSZ * 2;     // 16.8 MB
  __bf16* vtb   = (__bf16*)p; p += (size_t)NKV * HD * T_TOK * 2; // 2.1 MB [4][128][2048]

  // 1. casts / transposes
  cast_f32_bf16<<<(T_TOK * HID / 4) / 256, 256, 0, stream>>>(hs, hsb, T_TOK * HID / 4);
  transpose_cast<<<dim3(QKV_N / 64, HID / 64), 256, 0, stream>>>(wqkv, wqkvT, HID, QKV_N);
  transpose_cast<<<dim3(HID / 64, QSZ / 64), 256, 0, stream>>>(wo, woT, QSZ, HID);
  // 2. QKV projection
  gemm_bt<0><<<dim3(QKV_N / 128, T_TOK / 128), 256, 0, stream>>>(hsb, wqkvT, qkvb,
                                                                 T_TOK, QKV_N, HID);
  // 3. RMSNorm + RoPE in place on q,k
  norm_rope<<<dim3(T_TOK, NH + NKV), 128, 0, stream>>>(qkvb, pos, qw, kw);
  // 4. V transpose to [kvh][d][t]
  v_transpose<<<dim3(T_TOK / 64, HD / 64, NKV), 256, 0, stream>>>(qkvb, vtb);
  // 5. causal GQA flash attention
  flash_attn2<<<dim3(64, 8), 256, 0, stream>>>(qkvb, vtb, attnb);
  // 6. output projection
  gemm_bt<1><<<dim3(HID / 128, T_TOK / 128), 256, 0, stream>>>(attnb, woT, out,
                                                               T_TOK, HID, QSZ);
}

// Round 3
// 364.951 us; speedup vs baseline: 2.7137x; 1.0564x over previous
//
#include <hip/hip_runtime.h>
#include <hip/hip_bf16.h>

typedef __attribute__((ext_vector_type(8))) __bf16 bf16x8;
typedef __attribute__((ext_vector_type(4))) __bf16 bf16x4;
typedef __attribute__((ext_vector_type(4))) float f32x4;

#define T_TOK 2048
#define NH 32
#define NKV 4
#define HD 128
#define HID 2048
#define QKV_N 5120   // (32 + 2*4) * 128
#define QSZ 4096     // 32*128
#define KOFF 4096
#define VOFF 4608
#define ATT_N 4096

#define GLOAD_LDS16(g, l)                                              \
  __builtin_amdgcn_global_load_lds(                                    \
      (const __attribute__((address_space(1))) void*)(g),              \
      (__attribute__((address_space(3))) void*)(l), 16, 0, 0)

// ---------------- cast fp32 -> bf16 (row-major, vectorized) ----------------
__global__ __launch_bounds__(256) void cast_f32_bf16(const float* __restrict__ in,
                                                     __bf16* __restrict__ out, int n4) {
  int i = blockIdx.x * 256 + threadIdx.x;
  if (i < n4) {
    float4 v = reinterpret_cast<const float4*>(in)[i];
    bf16x4 o;
    o[0] = (__bf16)v.x; o[1] = (__bf16)v.y; o[2] = (__bf16)v.z; o[3] = (__bf16)v.w;
    reinterpret_cast<bf16x4*>(out)[i] = o;
  }
}

// ------------- cast + transpose: in fp32 [R][C] -> out bf16 [C][R] ---------
__global__ __launch_bounds__(256) void transpose_cast(const float* __restrict__ in,
                                                      __bf16* __restrict__ out,
                                                      int R, int C) {
  __shared__ float tile[64][65];
  int c0 = blockIdx.x * 64;
  int r0 = blockIdx.y * 64;
  int tx = threadIdx.x & 63;
  int ty = threadIdx.x >> 6;  // 0..3
#pragma unroll
  for (int i = 0; i < 64; i += 4)
    tile[ty + i][tx] = in[(size_t)(r0 + ty + i) * C + c0 + tx];
  __syncthreads();
#pragma unroll
  for (int i = 0; i < 64; i += 4)
    out[(size_t)(c0 + ty + i) * R + r0 + tx] = (__bf16)tile[tx][ty + i];
}

// ---- transpose V section of qkv: [t][kvh*128+d] -> vt[kvh][d][t] (bf16) ----
__global__ __launch_bounds__(256) void v_transpose(const __bf16* __restrict__ qkv,
                                                   __bf16* __restrict__ vt) {
  __shared__ __bf16 tile[64][72];
  int t0 = blockIdx.x * 64;
  int d0 = blockIdx.y * 64;
  int kvh = blockIdx.z;
  int tx = threadIdx.x & 63;
  int ty = threadIdx.x >> 6;
#pragma unroll
  for (int i = 0; i < 64; i += 4)
    tile[ty + i][tx] = qkv[(size_t)(t0 + ty + i) * QKV_N + VOFF + kvh * HD + d0 + tx];
  __syncthreads();
#pragma unroll
  for (int i = 0; i < 64; i += 4)
    vt[((size_t)kvh * HD + d0 + ty + i) * T_TOK + t0 + tx] = tile[tx][ty + i];
}

// ------- GEMM m97-structure: C[M][N] = A[M][K]*B^T, global_load_lds --------
// 128x128 tile, BK=32, linear LDS [128][32], 4 waves (2x2), 16 MFMA/K-step.
template <int OUTF32>
__global__ __launch_bounds__(256) void gemm_bt97(const __bf16* __restrict__ A,
                                                 const __bf16* __restrict__ B,
                                                 void* __restrict__ Cp,
                                                 int M, int N, int K) {
  __shared__ __attribute__((aligned(16))) __bf16 As[128][32];
  __shared__ __attribute__((aligned(16))) __bf16 Bs[128][32];
  const int tid = threadIdx.x;
  const int lane = tid & 63;
  const int wave = tid >> 6;
  const int la = lane & 15;
  const int lb = lane >> 4;
  const int wr = (wave >> 1) * 64;
  const int wc = (wave & 1) * 64;
  const int rowA0 = blockIdx.y * 128;
  const int rowB0 = blockIdx.x * 128;

  // staging: wave w DMAs rows [w*16, w*16+16) and [64+w*16, 64+w*16+16).
  // lane i -> row base+ i/4, col (i&3)*8  == linear base + lane*16 bytes.
  const int srow = wave * 16 + (lane >> 2);
  const int scol = (lane & 3) * 8;
  const __bf16* Asrc0 = &A[(size_t)(rowA0 + srow) * K + scol];
  const __bf16* Asrc1 = &A[(size_t)(rowA0 + 64 + srow) * K + scol];
  const __bf16* Bsrc0 = &B[(size_t)(rowB0 + srow) * K + scol];
  const __bf16* Bsrc1 = &B[(size_t)(rowB0 + 64 + srow) * K + scol];
  __bf16* Adst0 = &As[wave * 16][0];
  __bf16* Adst1 = &As[64 + wave * 16][0];
  __bf16* Bdst0 = &Bs[wave * 16][0];
  __bf16* Bdst1 = &Bs[64 + wave * 16][0];

  f32x4 acc[4][4] = {};

  for (int k0 = 0; k0 < K; k0 += 32) {
    __syncthreads();  // previous tile fully consumed
    GLOAD_LDS16(Asrc0 + k0, Adst0);
    GLOAD_LDS16(Asrc1 + k0, Adst1);
    GLOAD_LDS16(Bsrc0 + k0, Bdst0);
    GLOAD_LDS16(Bsrc1 + k0, Bdst1);
    __syncthreads();  // drains vmcnt -> tile visible

    bf16x8 af[4], bfr[4];
#pragma unroll
    for (int m = 0; m < 4; ++m)
      af[m] = *reinterpret_cast<const bf16x8*>(&As[wr + m * 16 + la][lb * 8]);
#pragma unroll
    for (int n = 0; n < 4; ++n)
      bfr[n] = *reinterpret_cast<const bf16x8*>(&Bs[wc + n * 16 + la][lb * 8]);
#pragma unroll
    for (int m = 0; m < 4; ++m)
#pragma unroll
      for (int n = 0; n < 4; ++n)
        acc[m][n] = __builtin_amdgcn_mfma_f32_16x16x32_bf16(af[m], bfr[n], acc[m][n], 0, 0, 0);
  }

#pragma unroll
  for (int m = 0; m < 4; ++m) {
#pragma unroll
    for (int n = 0; n < 4; ++n) {
#pragma unroll
      for (int r = 0; r < 4; ++r) {
        int row = rowA0 + wr + m * 16 + lb * 4 + r;
        int col = rowB0 + wc + n * 16 + la;
        if (OUTF32)
          reinterpret_cast<float*>(Cp)[(size_t)row * N + col] = acc[m][n][r];
        else
          reinterpret_cast<__bf16*>(Cp)[(size_t)row * N + col] = (__bf16)acc[m][n][r];
      }
    }
  }
}

// ---------------- RoPE cos/sin table: tab[t][0..63]=cos, [64..127]=sin -----
__global__ __launch_bounds__(64) void rope_table(const int* __restrict__ positions,
                                                 float* __restrict__ tab) {
  const int t = blockIdx.x;
  const int d = threadIdx.x;  // 0..63
  // 10000^(-d/64) = exp2(-d * log2(10000)/64)
  float freq = exp2f(-(float)d * 0.20762050593046015f);
  float fr = (float)positions[t] * freq;
  float c, s;
  sincosf(fr, &s, &c);
  tab[t * 128 + d] = c;
  tab[t * 128 + 64 + d] = s;
}

// ------------- RMSNorm + RoPE in-place on q/k rows of qkv buffer -----------
__global__ __launch_bounds__(128) void norm_rope(__bf16* __restrict__ qkv,
                                                 const float* __restrict__ tab,
                                                 const float* __restrict__ qw,
                                                 const float* __restrict__ kw) {
  const int t = blockIdx.x;
  const int head = blockIdx.y;  // 0..35: 0-31 q heads, 32-35 k heads
  const bool is_q = head < NH;
  const int col = is_q ? head * HD : KOFF + (head - NH) * HD;
  __bf16* row = qkv + (size_t)t * QKV_N + col;
  const int d = threadIdx.x;  // 0..127
  float x = (float)row[d];
  float ss = x * x;
#pragma unroll
  for (int mm = 1; mm < 64; mm <<= 1) ss += __shfl_xor(ss, mm);
  __shared__ float red[2];
  __shared__ float yl[128];
  if ((d & 63) == 0) red[d >> 6] = ss;
  __syncthreads();
  float var = (red[0] + red[1]) * (1.0f / 128.0f);
  float sc = rsqrtf(var + 1e-6f);
  const float* wv = is_q ? qw : kw;
  yl[d] = x * sc * wv[d];
  __syncthreads();
  if (d < 64) {
    float x1 = yl[d], x2 = yl[d + 64];
    float c = tab[t * 128 + d];
    float sn = tab[t * 128 + 64 + d];
    row[d] = (__bf16)(x1 * c - x2 * sn);
    row[d + 64] = (__bf16)(x2 * c + x1 * sn);
  }
}

// ------------- causal GQA flash attention, 4 waves = 4 heads / block --------
// grid (128, 8): qt = 127 - blockIdx.x (heaviest blocks dispatched first ->
// dynamic tail balancing); y: kvh = y>>1, head-half = y&1.
#define KVB 64
#define KS_LD 152   // 128 + 24 pad
#define VS_LD 88    // 64 + 24 pad
#define PL_LD 88

__global__ __launch_bounds__(256) void flash_attn3(const __bf16* __restrict__ qkv,
                                                   const __bf16* __restrict__ vt,
                                                   __bf16* __restrict__ attn) {
  __shared__ __attribute__((aligned(16))) __bf16 Ks[KVB][KS_LD];
  __shared__ __attribute__((aligned(16))) __bf16 Vs[HD][VS_LD];
  __shared__ __attribute__((aligned(16))) __bf16 pl[4][16][PL_LD];

  const int tid = threadIdx.x;
  const int lane = tid & 63;
  const int wave = tid >> 6;
  const int la = lane & 15;
  const int lb = lane >> 4;
  const int kvh = blockIdx.y >> 1;
  const int h = kvh * 8 + (blockIdx.y & 1) * 4 + wave;
  const __bf16* Kbase = qkv + KOFF + kvh * HD;
  const __bf16* Vbase = vt + (size_t)kvh * HD * T_TOK;

  // 1/sqrt(128) * log2(e): QK^T lands in log2 domain -> exp2 everywhere
  const float qscale = 0.088388347648318447f * 1.4426950408889634f;

  const int qt = 127 - (int)blockIdx.x;
  const int qb = qt * 16;

  bf16x8 qf[4];
  const __bf16* Qp = qkv + (size_t)(qb + la) * QKV_N + h * HD;
#pragma unroll
  for (int kk = 0; kk < 4; ++kk) {
    bf16x8 q = *reinterpret_cast<const bf16x8*>(Qp + kk * 32 + lb * 8);
#pragma unroll
    for (int j = 0; j < 8; ++j) q[j] = (__bf16)((float)q[j] * qscale);
    qf[kk] = q;
  }

  f32x4 acc[8] = {};
  float mrow[4] = {-1e30f, -1e30f, -1e30f, -1e30f};
  float lrow[4] = {0.0f, 0.0f, 0.0f, 0.0f};

  const int kvend = qb + 16;
  for (int kv0 = 0; kv0 < kvend; kv0 += KVB) {
    __syncthreads();  // previous tile fully consumed before overwrite
    // ---- cooperative stage: K[64][128] rows, V^T[128][64] rows ----
#pragma unroll
    for (int p = 0; p < 4; ++p) {
      int g = p * 256 + tid;
      int kr = g >> 4, kc = g & 15;
      bf16x8 k8 = *reinterpret_cast<const bf16x8*>(
          &Kbase[(size_t)(kv0 + kr) * QKV_N + kc * 8]);
      *reinterpret_cast<bf16x8*>(&Ks[kr][kc * 8]) = k8;
      int vr = g >> 3, vc = g & 7;
      bf16x8 v8 = *reinterpret_cast<const bf16x8*>(
          &Vbase[(size_t)vr * T_TOK + kv0 + vc * 8]);
      *reinterpret_cast<bf16x8*>(&Vs[vr][vc * 8]) = v8;
    }
    __syncthreads();

    // ---- QK^T: S[16 q][64 kv], log2 domain ----
    f32x4 st[4] = {};
#pragma unroll
    for (int n = 0; n < 4; ++n)
#pragma unroll
      for (int kk = 0; kk < 4; ++kk) {
        bf16x8 kf = *reinterpret_cast<const bf16x8*>(&Ks[n * 16 + la][kk * 32 + lb * 8]);
        st[n] = __builtin_amdgcn_mfma_f32_16x16x32_bf16(qf[kk], kf, st[n], 0, 0, 0);
      }

    // ---- online softmax with defer-max (THR=8 in log2 domain) ----
    const bool fullvalid = (kv0 + KVB - 1 <= qb);  // block-uniform
    float mnew4[4];
    bool need = false;
#pragma unroll
    for (int r = 0; r < 4; ++r) {
      const int row = qb + lb * 4 + r;
      float mx = -1e30f;
#pragma unroll
      for (int n = 0; n < 4; ++n) {
        float s = st[n][r];
        if (!fullvalid && (kv0 + n * 16 + la > row)) s = -1e30f;
        st[n][r] = s;
        mx = fmaxf(mx, s);
      }
#pragma unroll
      for (int mm = 1; mm < 16; mm <<= 1) mx = fmaxf(mx, __shfl_xor(mx, mm));
      mnew4[r] = mx;
      need = need || (mx > mrow[r] + 8.0f);
    }
    if (__any(need)) {
#pragma unroll
      for (int r = 0; r < 4; ++r) {
        float mnew = fmaxf(mrow[r], mnew4[r]);
        float corr = exp2f(mrow[r] - mnew);
        mrow[r] = mnew;
        lrow[r] *= corr;
#pragma unroll
        for (int dt = 0; dt < 8; ++dt) acc[dt][r] *= corr;
      }
    }
#pragma unroll
    for (int r = 0; r < 4; ++r) {
      float ps = 0.0f;
#pragma unroll
      for (int n = 0; n < 4; ++n) {
        float p = exp2f(st[n][r] - mrow[r]);
        ps += p;
        pl[wave][lb * 4 + r][n * 16 + la] = (__bf16)p;
      }
#pragma unroll
      for (int mm = 1; mm < 16; mm <<= 1) ps += __shfl_xor(ps, mm);
      lrow[r] += ps;
    }

    // ---- PV: out[16 q][128 d] += P[16][64] * V[64][128] ----
#pragma unroll
    for (int ks = 0; ks < 2; ++ks) {
      bf16x8 paf = *reinterpret_cast<const bf16x8*>(&pl[wave][la][ks * 32 + lb * 8]);
#pragma unroll
      for (int dt = 0; dt < 8; ++dt) {
        bf16x8 vbf = *reinterpret_cast<const bf16x8*>(&Vs[dt * 16 + la][ks * 32 + lb * 8]);
        acc[dt] = __builtin_amdgcn_mfma_f32_16x16x32_bf16(paf, vbf, acc[dt], 0, 0, 0);
      }
    }
  }

  // ---- epilogue ----
  float inv[4];
#pragma unroll
  for (int r = 0; r < 4; ++r) inv[r] = 1.0f / lrow[r];
#pragma unroll
  for (int dt = 0; dt < 8; ++dt)
#pragma unroll
    for (int r = 0; r < 4; ++r)
      attn[(size_t)(qb + lb * 4 + r) * ATT_N + h * HD + dt * 16 + la] =
          (__bf16)(acc[dt][r] * inv[r]);
}

extern "C" void kernel_launch(void* const* d_in, const int* in_sizes, int n_in,
                              void* d_out, int out_size, void* d_ws, size_t ws_size,
                              hipStream_t stream) {
  const float* hs   = (const float*)d_in[0];
  const int*   pos  = (const int*)d_in[1];
  const float* wqkv = (const float*)d_in[2];
  const float* wo   = (const float*)d_in[3];
  const float* qw   = (const float*)d_in[4];
  const float* kw   = (const float*)d_in[5];
  float* out = (float*)d_out;

  char* p = (char*)d_ws;
  __bf16* hsb   = (__bf16*)p; p += (size_t)T_TOK * HID * 2;      // 8.4 MB
  __bf16* wqkvT = (__bf16*)p; p += (size_t)QKV_N * HID * 2;      // 21 MB  [5120][2048]
  __bf16* woT   = (__bf16*)p; p += (size_t)HID * QSZ * 2;        // 16.8 MB [2048][4096]
  __bf16* qkvb  = (__bf16*)p; p += (size_t)T_TOK * QKV_N * 2;    // 21 MB
  __bf16* attnb = (__bf16*)p; p += (size_t)T_TOK * QSZ * 2;      // 16.8 MB
  __bf16* vtb   = (__bf16*)p; p += (size_t)NKV * HD * T_TOK * 2; // 2.1 MB [4][128][2048]
  float*  ropet = (float*)p;  p += (size_t)T_TOK * HD * 4;       // 1 MB [2048][128]

  // 1. casts / transposes / rope table
  cast_f32_bf16<<<(T_TOK * HID / 4) / 256, 256, 0, stream>>>(hs, hsb, T_TOK * HID / 4);
  transpose_cast<<<dim3(QKV_N / 64, HID / 64), 256, 0, stream>>>(wqkv, wqkvT, HID, QKV_N);
  transpose_cast<<<dim3(HID / 64, QSZ / 64), 256, 0, stream>>>(wo, woT, QSZ, HID);
  rope_table<<<T_TOK, 64, 0, stream>>>(pos, ropet);
  // 2. QKV projection
  gemm_bt97<0><<<dim3(QKV_N / 128, T_TOK / 128), 256, 0, stream>>>(hsb, wqkvT, qkvb,
                                                                   T_TOK, QKV_N, HID);
  // 3. RMSNorm + RoPE in place on q,k
  norm_rope<<<dim3(T_TOK, NH + NKV), 128, 0, stream>>>(qkvb, ropet, qw, kw);
  // 4. V transpose to [kvh][d][t]
  v_transpose<<<dim3(T_TOK / 64, HD / 64, NKV), 256, 0, stream>>>(qkvb, vtb);
  // 5. causal GQA flash attention (descending-work dispatch order)
  flash_attn3<<<dim3(128, 8), 256, 0, stream>>>(qkvb, vtb, attnb);
  // 6. output projection
  gemm_bt97<1><<<dim3(HID / 128, T_TOK / 128), 256, 0, stream>>>(attnb, woT, out,
                                                                 T_TOK, HID, QSZ);
}

// Round 4
// 346.824 us; speedup vs baseline: 2.8556x; 1.0523x over previous
//
#include <hip/hip_runtime.h>
#include <hip/hip_bf16.h>

typedef __attribute__((ext_vector_type(8))) __bf16 bf16x8;
typedef __attribute__((ext_vector_type(4))) __bf16 bf16x4;
typedef __attribute__((ext_vector_type(4))) float f32x4;

#define T_TOK 2048
#define NH 32
#define NKV 4
#define HD 128
#define HID 2048
#define QKV_N 5120   // (32 + 2*4) * 128
#define QSZ 4096     // 32*128
#define KOFF 4096
#define VOFF 4608
#define ATT_N 4096

#define GLOAD_LDS16(g, l)                                              \
  __builtin_amdgcn_global_load_lds(                                    \
      (const __attribute__((address_space(1))) void*)(g),              \
      (__attribute__((address_space(3))) void*)(l), 16, 0, 0)

// ---------------- cast fp32 -> bf16 (row-major, vectorized) ----------------
__global__ __launch_bounds__(256) void cast_f32_bf16(const float* __restrict__ in,
                                                     __bf16* __restrict__ out, int n4) {
  int i = blockIdx.x * 256 + threadIdx.x;
  if (i < n4) {
    float4 v = reinterpret_cast<const float4*>(in)[i];
    bf16x4 o;
    o[0] = (__bf16)v.x; o[1] = (__bf16)v.y; o[2] = (__bf16)v.z; o[3] = (__bf16)v.w;
    reinterpret_cast<bf16x4*>(out)[i] = o;
  }
}

// ------------- cast + transpose: in fp32 [R][C] -> out bf16 [C][R] ---------
// 4x4 register transpose, bf16x4 LDS writes, bf16x8 LDS reads + global writes.
__global__ __launch_bounds__(256) void transpose_cast(const float* __restrict__ in,
                                                      __bf16* __restrict__ out,
                                                      int R, int C) {
  __shared__ __attribute__((aligned(16))) __bf16 tile[64][72];  // [c][r]
  const int c0 = blockIdx.x * 64;
  const int r0 = blockIdx.y * 64;
  const int ca = (threadIdx.x & 15) * 4;  // col group
  const int ra = (threadIdx.x >> 4) * 4;  // row group
  float4 v[4];
#pragma unroll
  for (int i = 0; i < 4; ++i)
    v[i] = *reinterpret_cast<const float4*>(&in[(size_t)(r0 + ra + i) * C + c0 + ca]);
#pragma unroll
  for (int j = 0; j < 4; ++j) {
    bf16x4 o;
#pragma unroll
    for (int i = 0; i < 4; ++i) o[i] = (__bf16)(((const float*)&v[i])[j]);
    *reinterpret_cast<bf16x4*>(&tile[ca + j][ra]) = o;
  }
  __syncthreads();
#pragma unroll
  for (int i = 0; i < 2; ++i) {
    int c = i * 32 + (threadIdx.x >> 3);
    int r8 = (threadIdx.x & 7) * 8;
    bf16x8 o = *reinterpret_cast<const bf16x8*>(&tile[c][r8]);
    *reinterpret_cast<bf16x8*>(&out[(size_t)(c0 + c) * R + r0 + r8]) = o;
  }
}

// ---- transpose V section of qkv: [t][kvh*128+d] -> vt[kvh][d][t] (bf16) ----
__global__ __launch_bounds__(256) void v_transpose(const __bf16* __restrict__ qkv,
                                                   __bf16* __restrict__ vt) {
  __shared__ __bf16 tile[64][72];
  int t0 = blockIdx.x * 64;
  int d0 = blockIdx.y * 64;
  int kvh = blockIdx.z;
  int tx = threadIdx.x & 63;
  int ty = threadIdx.x >> 6;
#pragma unroll
  for (int i = 0; i < 64; i += 4)
    tile[ty + i][tx] = qkv[(size_t)(t0 + ty + i) * QKV_N + VOFF + kvh * HD + d0 + tx];
  __syncthreads();
#pragma unroll
  for (int i = 0; i < 64; i += 4)
    vt[((size_t)kvh * HD + d0 + ty + i) * T_TOK + t0 + tx] = tile[tx][ty + i];
}

// ------- GEMM m97-structure: C[M][N] = A[M][K]*B^T, global_load_lds --------
template <int OUTF32>
__global__ __launch_bounds__(256) void gemm_bt97(const __bf16* __restrict__ A,
                                                 const __bf16* __restrict__ B,
                                                 void* __restrict__ Cp,
                                                 int M, int N, int K) {
  __shared__ __attribute__((aligned(16))) __bf16 As[128][32];
  __shared__ __attribute__((aligned(16))) __bf16 Bs[128][32];
  const int tid = threadIdx.x;
  const int lane = tid & 63;
  const int wave = tid >> 6;
  const int la = lane & 15;
  const int lb = lane >> 4;
  const int wr = (wave >> 1) * 64;
  const int wc = (wave & 1) * 64;
  const int rowA0 = blockIdx.y * 128;
  const int rowB0 = blockIdx.x * 128;

  const int srow = wave * 16 + (lane >> 2);
  const int scol = (lane & 3) * 8;
  const __bf16* Asrc0 = &A[(size_t)(rowA0 + srow) * K + scol];
  const __bf16* Asrc1 = &A[(size_t)(rowA0 + 64 + srow) * K + scol];
  const __bf16* Bsrc0 = &B[(size_t)(rowB0 + srow) * K + scol];
  const __bf16* Bsrc1 = &B[(size_t)(rowB0 + 64 + srow) * K + scol];
  __bf16* Adst0 = &As[wave * 16][0];
  __bf16* Adst1 = &As[64 + wave * 16][0];
  __bf16* Bdst0 = &Bs[wave * 16][0];
  __bf16* Bdst1 = &Bs[64 + wave * 16][0];

  f32x4 acc[4][4] = {};

  for (int k0 = 0; k0 < K; k0 += 32) {
    __syncthreads();
    GLOAD_LDS16(Asrc0 + k0, Adst0);
    GLOAD_LDS16(Asrc1 + k0, Adst1);
    GLOAD_LDS16(Bsrc0 + k0, Bdst0);
    GLOAD_LDS16(Bsrc1 + k0, Bdst1);
    __syncthreads();

    bf16x8 af[4], bfr[4];
#pragma unroll
    for (int m = 0; m < 4; ++m)
      af[m] = *reinterpret_cast<const bf16x8*>(&As[wr + m * 16 + la][lb * 8]);
#pragma unroll
    for (int n = 0; n < 4; ++n)
      bfr[n] = *reinterpret_cast<const bf16x8*>(&Bs[wc + n * 16 + la][lb * 8]);
#pragma unroll
    for (int m = 0; m < 4; ++m)
#pragma unroll
      for (int n = 0; n < 4; ++n)
        acc[m][n] = __builtin_amdgcn_mfma_f32_16x16x32_bf16(af[m], bfr[n], acc[m][n], 0, 0, 0);
  }

#pragma unroll
  for (int m = 0; m < 4; ++m) {
#pragma unroll
    for (int n = 0; n < 4; ++n) {
#pragma unroll
      for (int r = 0; r < 4; ++r) {
        int row = rowA0 + wr + m * 16 + lb * 4 + r;
        int col = rowB0 + wc + n * 16 + la;
        if (OUTF32)
          reinterpret_cast<float*>(Cp)[(size_t)row * N + col] = acc[m][n][r];
        else
          reinterpret_cast<__bf16*>(Cp)[(size_t)row * N + col] = (__bf16)acc[m][n][r];
      }
    }
  }
}

// ---------------- RoPE cos/sin table: tab[t][0..63]=cos, [64..127]=sin -----
__global__ __launch_bounds__(64) void rope_table(const int* __restrict__ positions,
                                                 float* __restrict__ tab) {
  const int t = blockIdx.x;
  const int d = threadIdx.x;  // 0..63
  float freq = exp2f(-(float)d * 0.20762050593046015f);
  float fr = (float)positions[t] * freq;
  float c, s;
  sincosf(fr, &s, &c);
  tab[t * 128 + d] = c;
  tab[t * 128 + 64 + d] = s;
}

// ------------- RMSNorm + RoPE in-place on q/k rows of qkv buffer -----------
__global__ __launch_bounds__(128) void norm_rope(__bf16* __restrict__ qkv,
                                                 const float* __restrict__ tab,
                                                 const float* __restrict__ qw,
                                                 const float* __restrict__ kw) {
  const int t = blockIdx.x;
  const int head = blockIdx.y;
  const bool is_q = head < NH;
  const int col = is_q ? head * HD : KOFF + (head - NH) * HD;
  __bf16* row = qkv + (size_t)t * QKV_N + col;
  const int d = threadIdx.x;
  float x = (float)row[d];
  float ss = x * x;
#pragma unroll
  for (int mm = 1; mm < 64; mm <<= 1) ss += __shfl_xor(ss, mm);
  __shared__ float red[2];
  __shared__ float yl[128];
  if ((d & 63) == 0) red[d >> 6] = ss;
  __syncthreads();
  float var = (red[0] + red[1]) * (1.0f / 128.0f);
  float sc = rsqrtf(var + 1e-6f);
  const float* wv = is_q ? qw : kw;
  yl[d] = x * sc * wv[d];
  __syncthreads();
  if (d < 64) {
    float x1 = yl[d], x2 = yl[d + 64];
    float c = tab[t * 128 + d];
    float sn = tab[t * 128 + 64 + d];
    row[d] = (__bf16)(x1 * c - x2 * sn);
    row[d + 64] = (__bf16)(x2 * c + x1 * sn);
  }
}

// ---- causal GQA flash attention: 8 waves = full GQA group (8 heads) -------
// grid (128, 4): qt = 127 - bx (big blocks first). K/V staged cooperatively,
// T14 async staging (regs prefetched, ds_write next iter), XOR-swizzled LDS.
#define KVB 64

__global__ __launch_bounds__(512, 4) void flash_attn4(const __bf16* __restrict__ qkv,
                                                      const __bf16* __restrict__ vt,
                                                      __bf16* __restrict__ attn) {
  __shared__ __attribute__((aligned(16))) __bf16 Ks[64 * 128];
  __shared__ __attribute__((aligned(16))) __bf16 Vs[128 * 64];
  __shared__ __attribute__((aligned(16))) __bf16 pl[8][16][72];

  const int tid = threadIdx.x;
  const int lane = tid & 63;
  const int wave = tid >> 6;  // 0..7 = head within GQA group
  const int la = lane & 15;
  const int lb = lane >> 4;
  const int kvh = blockIdx.y;
  const int h = kvh * 8 + wave;
  const __bf16* Kbase = qkv + KOFF + kvh * HD;
  const __bf16* Vbase = vt + (size_t)kvh * HD * T_TOK;

  const float qscale = 0.088388347648318447f * 1.4426950408889634f;  // rsqrt(D)*log2e
  const int qt = 127 - (int)blockIdx.x;
  const int qb = qt * 16;
  const int kvend = qb + 16;

  // ---- Q fragments (per wave/head) ----
  bf16x8 qf[4];
  {
    const __bf16* Qp = qkv + (size_t)(qb + la) * QKV_N + h * HD;
#pragma unroll
    for (int kk = 0; kk < 4; ++kk) {
      bf16x8 q = *reinterpret_cast<const bf16x8*>(Qp + kk * 32 + lb * 8);
#pragma unroll
      for (int j = 0; j < 8; ++j) q[j] = (__bf16)((float)q[j] * qscale);
      qf[kk] = q;
    }
  }

  // ---- staging geometry (512 threads, 2 passes each for K and V) ----
  const int kr0 = tid >> 4;           // K rows 0..31 (pass0), +32 (pass1)
  const int kc = (tid & 15) * 8;
  const int kr1 = 32 + kr0;
  const int kw0 = kr0 * 256 + ((kc * 2) ^ ((kr0 & 7) << 4));
  const int kw1 = kr1 * 256 + ((kc * 2) ^ ((kr1 & 7) << 4));
  const int vr0 = tid >> 3;           // V^T rows 0..63 (pass0), +64 (pass1)
  const int vc = (tid & 7) * 8;
  const int vr1 = 64 + vr0;
  const int vw0 = vr0 * 128 + ((vc * 2) ^ ((vr0 & 7) << 4));
  const int vw1 = vr1 * 128 + ((vc * 2) ^ ((vr1 & 7) << 4));
  const __bf16* ksrc0 = Kbase + (size_t)kr0 * QKV_N + kc;
  const __bf16* ksrc1 = Kbase + (size_t)kr1 * QKV_N + kc;
  const __bf16* vsrc0 = Vbase + (size_t)vr0 * T_TOK + vc;
  const __bf16* vsrc1 = Vbase + (size_t)vr1 * T_TOK + vc;
  char* KsB = (char*)Ks;
  char* VsB = (char*)Vs;

  // prologue: tile 0 into registers
  bf16x8 krg0 = *reinterpret_cast<const bf16x8*>(ksrc0);
  bf16x8 krg1 = *reinterpret_cast<const bf16x8*>(ksrc1);
  bf16x8 vrg0 = *reinterpret_cast<const bf16x8*>(vsrc0);
  bf16x8 vrg1 = *reinterpret_cast<const bf16x8*>(vsrc1);

  f32x4 acc[8] = {};
  float mrow[4] = {-1e30f, -1e30f, -1e30f, -1e30f};
  float lrow[4] = {0.0f, 0.0f, 0.0f, 0.0f};

  for (int kv0 = 0; kv0 < kvend; kv0 += KVB) {
    __syncthreads();  // all waves done reading previous K/V tile
    *reinterpret_cast<bf16x8*>(KsB + kw0) = krg0;
    *reinterpret_cast<bf16x8*>(KsB + kw1) = krg1;
    *reinterpret_cast<bf16x8*>(VsB + vw0) = vrg0;
    *reinterpret_cast<bf16x8*>(VsB + vw1) = vrg1;
    const int nxt = kv0 + KVB;
    if (nxt < kvend) {  // prefetch next tile; in flight across compute
      krg0 = *reinterpret_cast<const bf16x8*>(ksrc0 + (size_t)nxt * QKV_N);
      krg1 = *reinterpret_cast<const bf16x8*>(ksrc1 + (size_t)nxt * QKV_N);
      vrg0 = *reinterpret_cast<const bf16x8*>(vsrc0 + nxt);
      vrg1 = *reinterpret_cast<const bf16x8*>(vsrc1 + nxt);
    }
    __syncthreads();  // K/V tile visible

    // ---- QK^T: S[16 q][64 kv], log2 domain ----
    f32x4 st[4] = {};
    __builtin_amdgcn_s_setprio(1);
#pragma unroll
    for (int n = 0; n < 4; ++n) {
      const int row = n * 16 + la;
#pragma unroll
      for (int kk = 0; kk < 4; ++kk) {
        bf16x8 kf = *reinterpret_cast<const bf16x8*>(
            KsB + row * 256 + ((kk * 64 + lb * 16) ^ ((row & 7) << 4)));
        st[n] = __builtin_amdgcn_mfma_f32_16x16x32_bf16(qf[kk], kf, st[n], 0, 0, 0);
      }
    }
    __builtin_amdgcn_s_setprio(0);

    // ---- online softmax with defer-max (THR=8, log2 domain) ----
    const bool fullvalid = (kv0 + KVB - 1 <= qb);
    float mnew4[4];
    bool need = false;
#pragma unroll
    for (int r = 0; r < 4; ++r) {
      const int row = qb + lb * 4 + r;
      float mx = -1e30f;
#pragma unroll
      for (int n = 0; n < 4; ++n) {
        float s = st[n][r];
        if (!fullvalid && (kv0 + n * 16 + la > row)) s = -1e30f;
        st[n][r] = s;
        mx = fmaxf(mx, s);
      }
#pragma unroll
      for (int mm = 1; mm < 16; mm <<= 1) mx = fmaxf(mx, __shfl_xor(mx, mm));
      mnew4[r] = mx;
      need = need || (mx > mrow[r] + 8.0f);
    }
    if (__any(need)) {
#pragma unroll
      for (int r = 0; r < 4; ++r) {
        float mnew = fmaxf(mrow[r], mnew4[r]);
        float corr = exp2f(mrow[r] - mnew);
        mrow[r] = mnew;
        lrow[r] *= corr;
#pragma unroll
        for (int dt = 0; dt < 8; ++dt) acc[dt][r] *= corr;
      }
    }
#pragma unroll
    for (int r = 0; r < 4; ++r) {
      float ps = 0.0f;
#pragma unroll
      for (int n = 0; n < 4; ++n) {
        float p = exp2f(st[n][r] - mrow[r]);
        ps += p;
        pl[wave][lb * 4 + r][n * 16 + la] = (__bf16)p;
      }
#pragma unroll
      for (int mm = 1; mm < 16; mm <<= 1) ps += __shfl_xor(ps, mm);
      lrow[r] += ps;
    }

    // ---- PV: out[16 q][128 d] += P[16][64] * V[64][128] ----
    __builtin_amdgcn_s_setprio(1);
#pragma unroll
    for (int ks = 0; ks < 2; ++ks) {
      bf16x8 paf = *reinterpret_cast<const bf16x8*>(&pl[wave][la][ks * 32 + lb * 8]);
#pragma unroll
      for (int dt = 0; dt < 8; ++dt) {
        const int row = dt * 16 + la;
        bf16x8 vbf = *reinterpret_cast<const bf16x8*>(
            VsB + row * 128 + ((ks * 64 + lb * 16) ^ ((row & 7) << 4)));
        acc[dt] = __builtin_amdgcn_mfma_f32_16x16x32_bf16(paf, vbf, acc[dt], 0, 0, 0);
      }
    }
    __builtin_amdgcn_s_setprio(0);
  }

  // ---- epilogue ----
  float inv[4];
#pragma unroll
  for (int r = 0; r < 4; ++r) inv[r] = 1.0f / lrow[r];
#pragma unroll
  for (int dt = 0; dt < 8; ++dt)
#pragma unroll
    for (int r = 0; r < 4; ++r)
      attn[(size_t)(qb + lb * 4 + r) * ATT_N + h * HD + dt * 16 + la] =
          (__bf16)(acc[dt][r] * inv[r]);
}

extern "C" void kernel_launch(void* const* d_in, const int* in_sizes, int n_in,
                              void* d_out, int out_size, void* d_ws, size_t ws_size,
                              hipStream_t stream) {
  const float* hs   = (const float*)d_in[0];
  const int*   pos  = (const int*)d_in[1];
  const float* wqkv = (const float*)d_in[2];
  const float* wo   = (const float*)d_in[3];
  const float* qw   = (const float*)d_in[4];
  const float* kw   = (const float*)d_in[5];
  float* out = (float*)d_out;

  char* p = (char*)d_ws;
  __bf16* hsb   = (__bf16*)p; p += (size_t)T_TOK * HID * 2;
  __bf16* wqkvT = (__bf16*)p; p += (size_t)QKV_N * HID * 2;
  __bf16* woT   = (__bf16*)p; p += (size_t)HID * QSZ * 2;
  __bf16* qkvb  = (__bf16*)p; p += (size_t)T_TOK * QKV_N * 2;
  __bf16* attnb = (__bf16*)p; p += (size_t)T_TOK * QSZ * 2;
  __bf16* vtb   = (__bf16*)p; p += (size_t)NKV * HD * T_TOK * 2;
  float*  ropet = (float*)p;  p += (size_t)T_TOK * HD * 4;

  cast_f32_bf16<<<(T_TOK * HID / 4) / 256, 256, 0, stream>>>(hs, hsb, T_TOK * HID / 4);
  transpose_cast<<<dim3(QKV_N / 64, HID / 64), 256, 0, stream>>>(wqkv, wqkvT, HID, QKV_N);
  transpose_cast<<<dim3(HID / 64, QSZ / 64), 256, 0, stream>>>(wo, woT, QSZ, HID);
  rope_table<<<T_TOK, 64, 0, stream>>>(pos, ropet);
  gemm_bt97<0><<<dim3(QKV_N / 128, T_TOK / 128), 256, 0, stream>>>(hsb, wqkvT, qkvb,
                                                                   T_TOK, QKV_N, HID);
  norm_rope<<<dim3(T_TOK, NH + NKV), 128, 0, stream>>>(qkvb, ropet, qw, kw);
  v_transpose<<<dim3(T_TOK / 64, HD / 64, NKV), 256, 0, stream>>>(qkvb, vtb);
  flash_attn4<<<dim3(128, NKV), 512, 0, stream>>>(qkvb, vtb, attnb);
  gemm_bt97<1><<<dim3(HID / 128, T_TOK / 128), 256, 0, stream>>>(attnb, woT, out,
                                                                 T_TOK, HID, QSZ);
}

// Round 5
// 305.244 us; speedup vs baseline: 3.2445x; 1.1362x over previous
//
#include <hip/hip_runtime.h>
#include <hip/hip_bf16.h>

typedef __attribute__((ext_vector_type(8))) __bf16 bf16x8;
typedef __attribute__((ext_vector_type(4))) __bf16 bf16x4;
typedef __attribute__((ext_vector_type(4))) float f32x4;
typedef __attribute__((ext_vector_type(16))) float f32x16;

#define T_TOK 2048
#define NH 32
#define NKV 4
#define HD 128
#define HID 2048
#define QKV_N 5120   // (32 + 2*4) * 128
#define QSZ 4096     // 32*128
#define KOFF 4096
#define VOFF 4608
#define ATT_N 4096

#define GLOAD_LDS16(g, l)                                              \
  __builtin_amdgcn_global_load_lds(                                    \
      (const __attribute__((address_space(1))) void*)(g),              \
      (__attribute__((address_space(3))) void*)(l), 16, 0, 0)

// ---------------- cast fp32 -> bf16 (row-major, vectorized) ----------------
__global__ __launch_bounds__(256) void cast_f32_bf16(const float* __restrict__ in,
                                                     __bf16* __restrict__ out, int n4) {
  int i = blockIdx.x * 256 + threadIdx.x;
  if (i < n4) {
    float4 v = reinterpret_cast<const float4*>(in)[i];
    bf16x4 o;
    o[0] = (__bf16)v.x; o[1] = (__bf16)v.y; o[2] = (__bf16)v.z; o[3] = (__bf16)v.w;
    reinterpret_cast<bf16x4*>(out)[i] = o;
  }
}

// ------------- cast + transpose: in fp32 [R][C] -> out bf16 [C][R] ---------
__global__ __launch_bounds__(256) void transpose_cast(const float* __restrict__ in,
                                                      __bf16* __restrict__ out,
                                                      int R, int C) {
  __shared__ __attribute__((aligned(16))) __bf16 tile[64][72];  // [c][r]
  const int c0 = blockIdx.x * 64;
  const int r0 = blockIdx.y * 64;
  const int ca = (threadIdx.x & 15) * 4;
  const int ra = (threadIdx.x >> 4) * 4;
  float4 v[4];
#pragma unroll
  for (int i = 0; i < 4; ++i)
    v[i] = *reinterpret_cast<const float4*>(&in[(size_t)(r0 + ra + i) * C + c0 + ca]);
#pragma unroll
  for (int j = 0; j < 4; ++j) {
    bf16x4 o;
#pragma unroll
    for (int i = 0; i < 4; ++i) o[i] = (__bf16)(((const float*)&v[i])[j]);
    *reinterpret_cast<bf16x4*>(&tile[ca + j][ra]) = o;
  }
  __syncthreads();
#pragma unroll
  for (int i = 0; i < 2; ++i) {
    int c = i * 32 + (threadIdx.x >> 3);
    int r8 = (threadIdx.x & 7) * 8;
    bf16x8 o = *reinterpret_cast<const bf16x8*>(&tile[c][r8]);
    *reinterpret_cast<bf16x8*>(&out[(size_t)(c0 + c) * R + r0 + r8]) = o;
  }
}

// ---- transpose V section of qkv: [t][kvh*128+d] -> vt[kvh][d][t] (bf16) ----
__global__ __launch_bounds__(256) void v_transpose(const __bf16* __restrict__ qkv,
                                                   __bf16* __restrict__ vt) {
  __shared__ __bf16 tile[64][72];
  int t0 = blockIdx.x * 64;
  int d0 = blockIdx.y * 64;
  int kvh = blockIdx.z;
  int tx = threadIdx.x & 63;
  int ty = threadIdx.x >> 6;
#pragma unroll
  for (int i = 0; i < 64; i += 4)
    tile[ty + i][tx] = qkv[(size_t)(t0 + ty + i) * QKV_N + VOFF + kvh * HD + d0 + tx];
  __syncthreads();
#pragma unroll
  for (int i = 0; i < 64; i += 4)
    vt[((size_t)kvh * HD + d0 + ty + i) * T_TOK + t0 + tx] = tile[tx][ty + i];
}

// ------- GEMM m97-structure: C[M][N] = A[M][K]*B^T, global_load_lds --------
template <int OUTF32>
__global__ __launch_bounds__(256) void gemm_bt97(const __bf16* __restrict__ A,
                                                 const __bf16* __restrict__ B,
                                                 void* __restrict__ Cp,
                                                 int M, int N, int K) {
  __shared__ __attribute__((aligned(16))) __bf16 As[128][32];
  __shared__ __attribute__((aligned(16))) __bf16 Bs[128][32];
  const int tid = threadIdx.x;
  const int lane = tid & 63;
  const int wave = tid >> 6;
  const int la = lane & 15;
  const int lb = lane >> 4;
  const int wr = (wave >> 1) * 64;
  const int wc = (wave & 1) * 64;
  const int rowA0 = blockIdx.y * 128;
  const int rowB0 = blockIdx.x * 128;

  const int srow = wave * 16 + (lane >> 2);
  const int scol = (lane & 3) * 8;
  const __bf16* Asrc0 = &A[(size_t)(rowA0 + srow) * K + scol];
  const __bf16* Asrc1 = &A[(size_t)(rowA0 + 64 + srow) * K + scol];
  const __bf16* Bsrc0 = &B[(size_t)(rowB0 + srow) * K + scol];
  const __bf16* Bsrc1 = &B[(size_t)(rowB0 + 64 + srow) * K + scol];
  __bf16* Adst0 = &As[wave * 16][0];
  __bf16* Adst1 = &As[64 + wave * 16][0];
  __bf16* Bdst0 = &Bs[wave * 16][0];
  __bf16* Bdst1 = &Bs[64 + wave * 16][0];

  f32x4 acc[4][4] = {};

  for (int k0 = 0; k0 < K; k0 += 32) {
    __syncthreads();
    GLOAD_LDS16(Asrc0 + k0, Adst0);
    GLOAD_LDS16(Asrc1 + k0, Adst1);
    GLOAD_LDS16(Bsrc0 + k0, Bdst0);
    GLOAD_LDS16(Bsrc1 + k0, Bdst1);
    __syncthreads();

    bf16x8 af[4], bfr[4];
#pragma unroll
    for (int m = 0; m < 4; ++m)
      af[m] = *reinterpret_cast<const bf16x8*>(&As[wr + m * 16 + la][lb * 8]);
#pragma unroll
    for (int n = 0; n < 4; ++n)
      bfr[n] = *reinterpret_cast<const bf16x8*>(&Bs[wc + n * 16 + la][lb * 8]);
#pragma unroll
    for (int m = 0; m < 4; ++m)
#pragma unroll
      for (int n = 0; n < 4; ++n)
        acc[m][n] = __builtin_amdgcn_mfma_f32_16x16x32_bf16(af[m], bfr[n], acc[m][n], 0, 0, 0);
  }

#pragma unroll
  for (int m = 0; m < 4; ++m) {
#pragma unroll
    for (int n = 0; n < 4; ++n) {
#pragma unroll
      for (int r = 0; r < 4; ++r) {
        int row = rowA0 + wr + m * 16 + lb * 4 + r;
        int col = rowB0 + wc + n * 16 + la;
        if (OUTF32)
          reinterpret_cast<float*>(Cp)[(size_t)row * N + col] = acc[m][n][r];
        else
          reinterpret_cast<__bf16*>(Cp)[(size_t)row * N + col] = (__bf16)acc[m][n][r];
      }
    }
  }
}

// ---------------- RoPE cos/sin table: tab[t][0..63]=cos, [64..127]=sin -----
__global__ __launch_bounds__(64) void rope_table(const int* __restrict__ positions,
                                                 float* __restrict__ tab) {
  const int t = blockIdx.x;
  const int d = threadIdx.x;
  float freq = exp2f(-(float)d * 0.20762050593046015f);
  float fr = (float)positions[t] * freq;
  float c, s;
  sincosf(fr, &s, &c);
  tab[t * 128 + d] = c;
  tab[t * 128 + 64 + d] = s;
}

// ------------- RMSNorm + RoPE in-place on q/k rows of qkv buffer -----------
__global__ __launch_bounds__(128) void norm_rope(__bf16* __restrict__ qkv,
                                                 const float* __restrict__ tab,
                                                 const float* __restrict__ qw,
                                                 const float* __restrict__ kw) {
  const int t = blockIdx.x;
  const int head = blockIdx.y;
  const bool is_q = head < NH;
  const int col = is_q ? head * HD : KOFF + (head - NH) * HD;
  __bf16* row = qkv + (size_t)t * QKV_N + col;
  const int d = threadIdx.x;
  float x = (float)row[d];
  float ss = x * x;
#pragma unroll
  for (int mm = 1; mm < 64; mm <<= 1) ss += __shfl_xor(ss, mm);
  __shared__ float red[2];
  __shared__ float yl[128];
  if ((d & 63) == 0) red[d >> 6] = ss;
  __syncthreads();
  float var = (red[0] + red[1]) * (1.0f / 128.0f);
  float sc = rsqrtf(var + 1e-6f);
  const float* wv = is_q ? qw : kw;
  yl[d] = x * sc * wv[d];
  __syncthreads();
  if (d < 64) {
    float x1 = yl[d], x2 = yl[d + 64];
    float c = tab[t * 128 + d];
    float sn = tab[t * 128 + 64 + d];
    row[d] = (__bf16)(x1 * c - x2 * sn);
    row[d + 64] = (__bf16)(x2 * c + x1 * sn);
  }
}

// ===== flash attention, swapped-QK^T 32x32 structure =====
// block = 4 waves = 4 heads (half GQA group), QBLK=32 rows, KVB=64.
// grid (64, 8). K/V double-buffered in LDS via global_load_lds (pre-swizzled
// source + swizzled reads), counted vmcnt, raw barriers. Softmax in-register.

__device__ __forceinline__ uint32_t pkbf(float a, float b) {
  union { __bf16 h; unsigned short u; } x, y;
  x.h = (__bf16)a;
  y.h = (__bf16)b;
  return (uint32_t)x.u | ((uint32_t)y.u << 16);
}

__global__ __launch_bounds__(256, 2) void flash_attn5(const __bf16* __restrict__ qkv,
                                                      const __bf16* __restrict__ vt,
                                                      __bf16* __restrict__ attn) {
  // 64KB: K dbuf 2x[64][128] then V^T dbuf 2x[128][64]
  __shared__ __attribute__((aligned(16))) __bf16 lds[32768];

  const int tid = threadIdx.x;
  const int lane = tid & 63;
  const int wave = tid >> 6;     // 0..3
  const int q5 = lane & 31;
  const int hi = lane >> 5;
  const int kvh = blockIdx.y >> 1;
  const int h = kvh * 8 + (blockIdx.y & 1) * 4 + wave;
  const __bf16* Kbase = qkv + KOFF + kvh * HD;
  const __bf16* Vbase = vt + (size_t)kvh * HD * T_TOK;

  const int qt = 63 - (int)blockIdx.x;   // big blocks dispatched first
  const int qb = qt * 32;
  const int qrow = qb + q5;
  const int nt = (qb + 32 + 63) >> 6;

  const float qscale = 0.088388347648318447f * 1.4426950408889634f;  // rsqrt(D)*log2e

  // Q fragments (B operand): lane holds Q[qb+q5][k0*16 + hi*8 .. +8]
  bf16x8 qf[8];
  {
    const __bf16* Qp = qkv + (size_t)(qb + q5) * QKV_N + h * HD + hi * 8;
#pragma unroll
    for (int k0 = 0; k0 < 8; ++k0) {
      bf16x8 q = *reinterpret_cast<const bf16x8*>(Qp + k0 * 16);
#pragma unroll
      for (int j = 0; j < 8; ++j) q[j] = (__bf16)((float)q[j] * qscale);
      qf[k0] = q;
    }
  }

  const int kc = (lane & 15) * 16;   // K stage byte col
  const int vc = (lane & 7) * 16;    // V stage byte col

  // stage one KV tile into buffer b: linear LDS dest (lane*16), swizzle folded
  // into the per-lane GLOBAL source column (rule #21 correct pattern).
#define STAGE5(b, kv00)                                                         \
  do {                                                                          \
    __bf16* kdst = lds + (b) * 8192;                                            \
    __bf16* vdst = lds + 16384 + (b) * 8192;                                    \
    _Pragma("unroll")                                                           \
    for (int i = 0; i < 4; ++i) {                                               \
      int kr = wave * 16 + i * 4 + (lane >> 4);                                 \
      int ksc = (kc ^ ((kr & 15) << 4)) >> 1;                                   \
      GLOAD_LDS16(Kbase + (size_t)((kv00) + kr) * QKV_N + ksc,                  \
                  kdst + (wave * 16 + i * 4) * 128);                            \
      int vr = wave * 32 + i * 8 + (lane >> 3);                                 \
      int vsc = (vc ^ ((vr & 7) << 4)) >> 1;                                    \
      GLOAD_LDS16(Vbase + (size_t)vr * T_TOK + (kv00) + vsc,                    \
                  vdst + (wave * 32 + i * 8) * 64);                             \
    }                                                                           \
  } while (0)

  f32x16 acc0 = {}, acc1 = {}, acc2 = {}, acc3 = {};
  float mrow = -1e30f, lrow = 0.0f;

  STAGE5(0, 0);

  int cur = 0;
  for (int t = 0; t < nt; ++t) {
    const int kv0 = t * 64;
    __builtin_amdgcn_s_barrier();          // all waves done reading buf[cur^1]
    __builtin_amdgcn_sched_barrier(0);
    if (t + 1 < nt) {
      STAGE5(cur ^ 1, kv0 + 64);           // prefetch stays in flight
      asm volatile("s_waitcnt vmcnt(8)" ::: "memory");
    } else {
      asm volatile("s_waitcnt vmcnt(0)" ::: "memory");
    }
    __builtin_amdgcn_s_barrier();          // tile t visible to all waves
    __builtin_amdgcn_sched_barrier(0);

    const char* Kt = (const char*)(lds + cur * 8192);
    const char* Vt = (const char*)(lds + 16384 + cur * 8192);

    // ---- swapped QK^T: st = K_tile · Q^T -> D[kv][q], log2 domain ----
    f32x16 st0 = {}, st1 = {};
    __builtin_amdgcn_s_setprio(1);
#pragma unroll
    for (int k0 = 0; k0 < 8; ++k0) {
      int cS = (k0 * 32 + hi * 16) ^ ((q5 & 15) << 4);
      bf16x8 a0 = *reinterpret_cast<const bf16x8*>(Kt + q5 * 256 + cS);
      bf16x8 a1 = *reinterpret_cast<const bf16x8*>(Kt + (32 + q5) * 256 + cS);
      st0 = __builtin_amdgcn_mfma_f32_32x32x16_bf16(a0, qf[k0], st0, 0, 0, 0);
      st1 = __builtin_amdgcn_mfma_f32_32x32x16_bf16(a1, qf[k0], st1, 0, 0, 0);
    }
    __builtin_amdgcn_s_setprio(0);

    // ---- mask (diagonal tiles only) + in-register online softmax ----
    if (!(kv0 + 63 <= qb)) {
#pragma unroll
      for (int r = 0; r < 16; ++r) {
        int kp = kv0 + (r & 3) + 8 * (r >> 2) + 4 * hi;  // crow(r,hi)
        if (kp > qrow) st0[r] = -1e30f;
        if (kp + 32 > qrow) st1[r] = -1e30f;
      }
    }
    float mx = -1e30f;
#pragma unroll
    for (int r = 0; r < 16; ++r) mx = fmaxf(mx, fmaxf(st0[r], st1[r]));
    mx = fmaxf(mx, __shfl_xor(mx, 32));
    if (__any(mx > mrow + 8.0f)) {          // defer-max THR=8 (log2 domain)
      float mnew = fmaxf(mrow, mx);
      float corr = exp2f(mrow - mnew);
      lrow *= corr;
      acc0 *= corr; acc1 *= corr; acc2 *= corr; acc3 *= corr;
      mrow = mnew;
    }
    float ps = 0.0f;
#pragma unroll
    for (int r = 0; r < 16; ++r) {
      float p0 = exp2f(st0[r] - mrow);
      float p1 = exp2f(st1[r] - mrow);
      ps += p0 + p1;
      st0[r] = p0;
      st1[r] = p1;
    }
    ps += __shfl_xor(ps, 32);
    lrow += ps;

    // ---- pack P rows to bf16 words: W[m] rows (8*(m>>1)+2*(m&1)+4hi, +1) ----
    uint32_t W0[8], W1[8];
#pragma unroll
    for (int m = 0; m < 8; ++m) {
      W0[m] = pkbf(st0[2 * m], st0[2 * m + 1]);
      W1[m] = pkbf(st1[2 * m], st1[2 * m + 1]);
    }

    // ---- PV: acc[dt] += V^T_frag · P^T_frag (D[d][q]) ----
    const bool hib = (hi != 0);
#pragma unroll
    for (int ks = 0; ks < 4; ++ks) {
      const int j = 4 * (ks & 1);
      uint32_t wj0, wj1, wj2, wj3;
      if (ks < 2) { wj0 = W0[j]; wj1 = W0[j + 1]; wj2 = W0[j + 2]; wj3 = W0[j + 3]; }
      else        { wj0 = W1[j]; wj1 = W1[j + 1]; wj2 = W1[j + 2]; wj3 = W1[j + 3]; }
      uint32_t keepA = hib ? wj2 : wj0;
      uint32_t keepB = hib ? wj3 : wj1;
      uint32_t sendA = hib ? wj0 : wj2;
      uint32_t sendB = hib ? wj1 : wj3;
      uint32_t recvA = (uint32_t)__shfl_xor((int)sendA, 32);
      uint32_t recvB = (uint32_t)__shfl_xor((int)sendB, 32);
      union { uint32_t u[4]; bf16x8 v; } fr;
      fr.u[0] = hib ? recvA : keepA;
      fr.u[1] = hib ? recvB : keepB;
      fr.u[2] = hib ? keepA : recvA;
      fr.u[3] = hib ? keepB : recvB;
      const int cV = (ks * 32 + hi * 16) ^ ((q5 & 7) << 4);
      __builtin_amdgcn_s_setprio(1);
      bf16x8 v0 = *reinterpret_cast<const bf16x8*>(Vt + (0 * 32 + q5) * 128 + cV);
      acc0 = __builtin_amdgcn_mfma_f32_32x32x16_bf16(v0, fr.v, acc0, 0, 0, 0);
      bf16x8 v1 = *reinterpret_cast<const bf16x8*>(Vt + (1 * 32 + q5) * 128 + cV);
      acc1 = __builtin_amdgcn_mfma_f32_32x32x16_bf16(v1, fr.v, acc1, 0, 0, 0);
      bf16x8 v2 = *reinterpret_cast<const bf16x8*>(Vt + (2 * 32 + q5) * 128 + cV);
      acc2 = __builtin_amdgcn_mfma_f32_32x32x16_bf16(v2, fr.v, acc2, 0, 0, 0);
      bf16x8 v3 = *reinterpret_cast<const bf16x8*>(Vt + (3 * 32 + q5) * 128 + cV);
      acc3 = __builtin_amdgcn_mfma_f32_32x32x16_bf16(v3, fr.v, acc3, 0, 0, 0);
      __builtin_amdgcn_s_setprio(0);
    }
    cur ^= 1;
  }

  // ---- epilogue: per-wave LDS transpose (reuse K area), coalesced store ----
  __syncthreads();
  {
    char* ob = (char*)lds + wave * 8192;   // [32 q][256B], swizzled (q&15)<<4
    float inv = 1.0f / lrow;
    const int swzE = (q5 & 15) << 4;
#pragma unroll
    for (int dt = 0; dt < 4; ++dt) {
      f32x16 a = dt == 0 ? acc0 : dt == 1 ? acc1 : dt == 2 ? acc2 : acc3;
#pragma unroll
      for (int t4 = 0; t4 < 4; ++t4) {
        uint2 wv;
        wv.x = pkbf(a[4 * t4] * inv, a[4 * t4 + 1] * inv);
        wv.y = pkbf(a[4 * t4 + 2] * inv, a[4 * t4 + 3] * inv);
        int d2 = (dt * 32 + 8 * t4 + 4 * hi) * 2;
        *reinterpret_cast<uint2*>(ob + q5 * 256 + (d2 ^ swzE)) = wv;
      }
    }
#pragma unroll
    for (int rr = 0; rr < 8; ++rr) {
      int idx = rr * 64 + lane;
      int q = idx >> 4;
      int cc = (idx & 15) * 16;
      bf16x8 o = *reinterpret_cast<const bf16x8*>(ob + q * 256 + (cc ^ ((q & 15) << 4)));
      *reinterpret_cast<bf16x8*>(&attn[(size_t)(qb + q) * ATT_N + h * HD + (cc >> 1)]) = o;
    }
  }
}

extern "C" void kernel_launch(void* const* d_in, const int* in_sizes, int n_in,
                              void* d_out, int out_size, void* d_ws, size_t ws_size,
                              hipStream_t stream) {
  const float* hs   = (const float*)d_in[0];
  const int*   pos  = (const int*)d_in[1];
  const float* wqkv = (const float*)d_in[2];
  const float* wo   = (const float*)d_in[3];
  const float* qw   = (const float*)d_in[4];
  const float* kw   = (const float*)d_in[5];
  float* out = (float*)d_out;

  char* p = (char*)d_ws;
  __bf16* hsb   = (__bf16*)p; p += (size_t)T_TOK * HID * 2;
  __bf16* wqkvT = (__bf16*)p; p += (size_t)QKV_N * HID * 2;
  __bf16* woT   = (__bf16*)p; p += (size_t)HID * QSZ * 2;
  __bf16* qkvb  = (__bf16*)p; p += (size_t)T_TOK * QKV_N * 2;
  __bf16* attnb = (__bf16*)p; p += (size_t)T_TOK * QSZ * 2;
  __bf16* vtb   = (__bf16*)p; p += (size_t)NKV * HD * T_TOK * 2;
  float*  ropet = (float*)p;  p += (size_t)T_TOK * HD * 4;

  cast_f32_bf16<<<(T_TOK * HID / 4) / 256, 256, 0, stream>>>(hs, hsb, T_TOK * HID / 4);
  transpose_cast<<<dim3(QKV_N / 64, HID / 64), 256, 0, stream>>>(wqkv, wqkvT, HID, QKV_N);
  transpose_cast<<<dim3(HID / 64, QSZ / 64), 256, 0, stream>>>(wo, woT, QSZ, HID);
  rope_table<<<T_TOK, 64, 0, stream>>>(pos, ropet);
  gemm_bt97<0><<<dim3(QKV_N / 128, T_TOK / 128), 256, 0, stream>>>(hsb, wqkvT, qkvb,
                                                                   T_TOK, QKV_N, HID);
  norm_rope<<<dim3(T_TOK, NH + NKV), 128, 0, stream>>>(qkvb, ropet, qw, kw);
  v_transpose<<<dim3(T_TOK / 64, HD / 64, NKV), 256, 0, stream>>>(qkvb, vtb);
  flash_attn5<<<dim3(64, 8), 256, 0, stream>>>(qkvb, vtb, attnb);
  gemm_bt97<1><<<dim3(HID / 128, T_TOK / 128), 256, 0, stream>>>(attnb, woT, out,
                                                                 T_TOK, HID, QSZ);
}

// Round 6
// 286.829 us; speedup vs baseline: 3.4528x; 1.0642x over previous
//
#include <hip/hip_runtime.h>
#include <hip/hip_bf16.h>

typedef __attribute__((ext_vector_type(8))) __bf16 bf16x8;
typedef __attribute__((ext_vector_type(4))) __bf16 bf16x4;
typedef __attribute__((ext_vector_type(4))) float f32x4;
typedef __attribute__((ext_vector_type(16))) float f32x16;

#define T_TOK 2048
#define NH 32
#define NKV 4
#define HD 128
#define HID 2048
#define QKV_N 5120   // (32 + 2*4) * 128
#define QSZ 4096     // 32*128
#define KOFF 4096
#define VOFF 4608
#define ATT_N 4096

#define GLOAD_LDS16(g, l)                                              \
  __builtin_amdgcn_global_load_lds(                                    \
      (const __attribute__((address_space(1))) void*)(g),              \
      (__attribute__((address_space(3))) void*)(l), 16, 0, 0)

// ---------------- cast fp32 -> bf16 (row-major, vectorized) ----------------
__global__ __launch_bounds__(256) void cast_f32_bf16(const float* __restrict__ in,
                                                     __bf16* __restrict__ out, int n4) {
  int i = blockIdx.x * 256 + threadIdx.x;
  if (i < n4) {
    float4 v = reinterpret_cast<const float4*>(in)[i];
    bf16x4 o;
    o[0] = (__bf16)v.x; o[1] = (__bf16)v.y; o[2] = (__bf16)v.z; o[3] = (__bf16)v.w;
    reinterpret_cast<bf16x4*>(out)[i] = o;
  }
}

// ------------- cast + transpose: in fp32 [R][C] -> out bf16 [C][R] ---------
__global__ __launch_bounds__(256) void transpose_cast(const float* __restrict__ in,
                                                      __bf16* __restrict__ out,
                                                      int R, int C) {
  __shared__ __attribute__((aligned(16))) __bf16 tile[64][72];  // [c][r]
  const int c0 = blockIdx.x * 64;
  const int r0 = blockIdx.y * 64;
  const int ca = (threadIdx.x & 15) * 4;
  const int ra = (threadIdx.x >> 4) * 4;
  float4 v[4];
#pragma unroll
  for (int i = 0; i < 4; ++i)
    v[i] = *reinterpret_cast<const float4*>(&in[(size_t)(r0 + ra + i) * C + c0 + ca]);
#pragma unroll
  for (int j = 0; j < 4; ++j) {
    bf16x4 o;
#pragma unroll
    for (int i = 0; i < 4; ++i) o[i] = (__bf16)(((const float*)&v[i])[j]);
    *reinterpret_cast<bf16x4*>(&tile[ca + j][ra]) = o;
  }
  __syncthreads();
#pragma unroll
  for (int i = 0; i < 2; ++i) {
    int c = i * 32 + (threadIdx.x >> 3);
    int r8 = (threadIdx.x & 7) * 8;
    bf16x8 o = *reinterpret_cast<const bf16x8*>(&tile[c][r8]);
    *reinterpret_cast<bf16x8*>(&out[(size_t)(c0 + c) * R + r0 + r8]) = o;
  }
}

// ---- transpose V section of qkv: [t][kvh*128+d] -> vt[kvh][d][t] (bf16) ----
__global__ __launch_bounds__(256) void v_transpose(const __bf16* __restrict__ qkv,
                                                   __bf16* __restrict__ vt) {
  __shared__ __bf16 tile[64][72];
  int t0 = blockIdx.x * 64;
  int d0 = blockIdx.y * 64;
  int kvh = blockIdx.z;
  int tx = threadIdx.x & 63;
  int ty = threadIdx.x >> 6;
#pragma unroll
  for (int i = 0; i < 64; i += 4)
    tile[ty + i][tx] = qkv[(size_t)(t0 + ty + i) * QKV_N + VOFF + kvh * HD + d0 + tx];
  __syncthreads();
#pragma unroll
  for (int i = 0; i < 64; i += 4)
    vt[((size_t)kvh * HD + d0 + ty + i) * T_TOK + t0 + tx] = tile[tx][ty + i];
}

// ====== GEMM, depth-2 pipelined: C[M][N] = A[M][K]*B^T (B stored [N][K]) ====
// 128x128 tile, BK=32, 3 LDS buffers, counted vmcnt (never 0 in steady state),
// raw s_barrier (no vmcnt drain). Flattened grid + bijective XCD swizzle.
template <int OUTF32>
__global__ __launch_bounds__(256) void gemm_db(const __bf16* __restrict__ A,
                                               const __bf16* __restrict__ B,
                                               void* __restrict__ Cp,
                                               int M, int N, int K, int nbx) {
  __shared__ __attribute__((aligned(16))) __bf16 As[3][128][32];
  __shared__ __attribute__((aligned(16))) __bf16 Bs[3][128][32];
  const int tid = threadIdx.x;
  const int lane = tid & 63;
  const int wave = tid >> 6;
  const int la = lane & 15;
  const int lb = lane >> 4;
  const int wr = (wave >> 1) * 64;
  const int wc = (wave & 1) * 64;

  // bijective XCD swizzle (grid size divisible by 8)
  const int nwg = gridDim.x;
  const int cpx = nwg >> 3;
  const int swz = ((int)blockIdx.x & 7) * cpx + ((int)blockIdx.x >> 3);
  const int bx = swz % nbx;
  const int by = swz / nbx;
  const int rowA0 = by * 128;
  const int rowB0 = bx * 128;

  const int srow = wave * 16 + (lane >> 2);
  const int scol = (lane & 3) * 8;
  const __bf16* Asrc0 = &A[(size_t)(rowA0 + srow) * K + scol];
  const __bf16* Asrc1 = &A[(size_t)(rowA0 + 64 + srow) * K + scol];
  const __bf16* Bsrc0 = &B[(size_t)(rowB0 + srow) * K + scol];
  const __bf16* Bsrc1 = &B[(size_t)(rowB0 + 64 + srow) * K + scol];

#define STAGEG(b, k0)                                            \
  do {                                                           \
    GLOAD_LDS16(Asrc0 + (k0), &As[b][wave * 16][0]);             \
    GLOAD_LDS16(Asrc1 + (k0), &As[b][64 + wave * 16][0]);        \
    GLOAD_LDS16(Bsrc0 + (k0), &Bs[b][wave * 16][0]);             \
    GLOAD_LDS16(Bsrc1 + (k0), &Bs[b][64 + wave * 16][0]);        \
  } while (0)

  f32x4 acc[4][4] = {};

  const int nt = K >> 5;
  STAGEG(0, 0);
  STAGEG(1, 32);

  for (int t = 0; t < nt; ++t) {
    const int cur = t % 3;
    if (t + 2 < nt) {
      STAGEG((t + 2) % 3, (t + 2) * 32);
      asm volatile("s_waitcnt vmcnt(8)" ::: "memory");   // tile t landed
    } else if (t + 1 < nt) {
      asm volatile("s_waitcnt vmcnt(4)" ::: "memory");
    } else {
      asm volatile("s_waitcnt vmcnt(0)" ::: "memory");
    }
    __builtin_amdgcn_sched_barrier(0);
    __builtin_amdgcn_s_barrier();        // tile t visible to all waves

    bf16x8 af[4], bfr[4];
#pragma unroll
    for (int m = 0; m < 4; ++m)
      af[m] = *reinterpret_cast<const bf16x8*>(&As[cur][wr + m * 16 + la][lb * 8]);
#pragma unroll
    for (int n = 0; n < 4; ++n)
      bfr[n] = *reinterpret_cast<const bf16x8*>(&Bs[cur][wc + n * 16 + la][lb * 8]);
#pragma unroll
    for (int m = 0; m < 4; ++m)
#pragma unroll
      for (int n = 0; n < 4; ++n)
        acc[m][n] = __builtin_amdgcn_mfma_f32_16x16x32_bf16(af[m], bfr[n], acc[m][n], 0, 0, 0);

    __builtin_amdgcn_s_barrier();        // all waves done reading buf cur
  }
#undef STAGEG

#pragma unroll
  for (int m = 0; m < 4; ++m) {
#pragma unroll
    for (int n = 0; n < 4; ++n) {
#pragma unroll
      for (int r = 0; r < 4; ++r) {
        int row = rowA0 + wr + m * 16 + lb * 4 + r;
        int col = rowB0 + wc + n * 16 + la;
        if (OUTF32)
          reinterpret_cast<float*>(Cp)[(size_t)row * N + col] = acc[m][n][r];
        else
          reinterpret_cast<__bf16*>(Cp)[(size_t)row * N + col] = (__bf16)acc[m][n][r];
      }
    }
  }
}

// ---------------- RoPE cos/sin table: tab[t][0..63]=cos, [64..127]=sin -----
__global__ __launch_bounds__(64) void rope_table(const int* __restrict__ positions,
                                                 float* __restrict__ tab) {
  const int t = blockIdx.x;
  const int d = threadIdx.x;
  float freq = exp2f(-(float)d * 0.20762050593046015f);
  float fr = (float)positions[t] * freq;
  float c, s;
  sincosf(fr, &s, &c);
  tab[t * 128 + d] = c;
  tab[t * 128 + 64 + d] = s;
}

// ------------- RMSNorm + RoPE in-place on q/k rows of qkv buffer -----------
__global__ __launch_bounds__(128) void norm_rope(__bf16* __restrict__ qkv,
                                                 const float* __restrict__ tab,
                                                 const float* __restrict__ qw,
                                                 const float* __restrict__ kw) {
  const int t = blockIdx.x;
  const int head = blockIdx.y;
  const bool is_q = head < NH;
  const int col = is_q ? head * HD : KOFF + (head - NH) * HD;
  __bf16* row = qkv + (size_t)t * QKV_N + col;
  const int d = threadIdx.x;
  float x = (float)row[d];
  float ss = x * x;
#pragma unroll
  for (int mm = 1; mm < 64; mm <<= 1) ss += __shfl_xor(ss, mm);
  __shared__ float red[2];
  __shared__ float yl[128];
  if ((d & 63) == 0) red[d >> 6] = ss;
  __syncthreads();
  float var = (red[0] + red[1]) * (1.0f / 128.0f);
  float sc = rsqrtf(var + 1e-6f);
  const float* wv = is_q ? qw : kw;
  yl[d] = x * sc * wv[d];
  __syncthreads();
  if (d < 64) {
    float x1 = yl[d], x2 = yl[d + 64];
    float c = tab[t * 128 + d];
    float sn = tab[t * 128 + 64 + d];
    row[d] = (__bf16)(x1 * c - x2 * sn);
    row[d + 64] = (__bf16)(x2 * c + x1 * sn);
  }
}

// ===== flash attention, swapped-QK^T 32x32 structure (unchanged from R5) ====
__device__ __forceinline__ uint32_t pkbf(float a, float b) {
  union { __bf16 h; unsigned short u; } x, y;
  x.h = (__bf16)a;
  y.h = (__bf16)b;
  return (uint32_t)x.u | ((uint32_t)y.u << 16);
}

__global__ __launch_bounds__(256, 2) void flash_attn5(const __bf16* __restrict__ qkv,
                                                      const __bf16* __restrict__ vt,
                                                      __bf16* __restrict__ attn) {
  __shared__ __attribute__((aligned(16))) __bf16 lds[32768];

  const int tid = threadIdx.x;
  const int lane = tid & 63;
  const int wave = tid >> 6;     // 0..3
  const int q5 = lane & 31;
  const int hi = lane >> 5;
  const int kvh = blockIdx.y >> 1;
  const int h = kvh * 8 + (blockIdx.y & 1) * 4 + wave;
  const __bf16* Kbase = qkv + KOFF + kvh * HD;
  const __bf16* Vbase = vt + (size_t)kvh * HD * T_TOK;

  const int qt = 63 - (int)blockIdx.x;
  const int qb = qt * 32;
  const int qrow = qb + q5;
  const int nt = (qb + 32 + 63) >> 6;

  const float qscale = 0.088388347648318447f * 1.4426950408889634f;

  bf16x8 qf[8];
  {
    const __bf16* Qp = qkv + (size_t)(qb + q5) * QKV_N + h * HD + hi * 8;
#pragma unroll
    for (int k0 = 0; k0 < 8; ++k0) {
      bf16x8 q = *reinterpret_cast<const bf16x8*>(Qp + k0 * 16);
#pragma unroll
      for (int j = 0; j < 8; ++j) q[j] = (__bf16)((float)q[j] * qscale);
      qf[k0] = q;
    }
  }

  const int kc = (lane & 15) * 16;
  const int vc = (lane & 7) * 16;

#define STAGE5(b, kv00)                                                         \
  do {                                                                          \
    __bf16* kdst = lds + (b) * 8192;                                            \
    __bf16* vdst = lds + 16384 + (b) * 8192;                                    \
    _Pragma("unroll")                                                           \
    for (int i = 0; i < 4; ++i) {                                               \
      int kr = wave * 16 + i * 4 + (lane >> 4);                                 \
      int ksc = (kc ^ ((kr & 15) << 4)) >> 1;                                   \
      GLOAD_LDS16(Kbase + (size_t)((kv00) + kr) * QKV_N + ksc,                  \
                  kdst + (wave * 16 + i * 4) * 128);                            \
      int vr = wave * 32 + i * 8 + (lane >> 3);                                 \
      int vsc = (vc ^ ((vr & 7) << 4)) >> 1;                                    \
      GLOAD_LDS16(Vbase + (size_t)vr * T_TOK + (kv00) + vsc,                    \
                  vdst + (wave * 32 + i * 8) * 64);                             \
    }                                                                           \
  } while (0)

  f32x16 acc0 = {}, acc1 = {}, acc2 = {}, acc3 = {};
  float mrow = -1e30f, lrow = 0.0f;

  STAGE5(0, 0);

  int cur = 0;
  for (int t = 0; t < nt; ++t) {
    const int kv0 = t * 64;
    __builtin_amdgcn_s_barrier();
    __builtin_amdgcn_sched_barrier(0);
    if (t + 1 < nt) {
      STAGE5(cur ^ 1, kv0 + 64);
      asm volatile("s_waitcnt vmcnt(8)" ::: "memory");
    } else {
      asm volatile("s_waitcnt vmcnt(0)" ::: "memory");
    }
    __builtin_amdgcn_s_barrier();
    __builtin_amdgcn_sched_barrier(0);

    const char* Kt = (const char*)(lds + cur * 8192);
    const char* Vt = (const char*)(lds + 16384 + cur * 8192);

    f32x16 st0 = {}, st1 = {};
    __builtin_amdgcn_s_setprio(1);
#pragma unroll
    for (int k0 = 0; k0 < 8; ++k0) {
      int cS = (k0 * 32 + hi * 16) ^ ((q5 & 15) << 4);
      bf16x8 a0 = *reinterpret_cast<const bf16x8*>(Kt + q5 * 256 + cS);
      bf16x8 a1 = *reinterpret_cast<const bf16x8*>(Kt + (32 + q5) * 256 + cS);
      st0 = __builtin_amdgcn_mfma_f32_32x32x16_bf16(a0, qf[k0], st0, 0, 0, 0);
      st1 = __builtin_amdgcn_mfma_f32_32x32x16_bf16(a1, qf[k0], st1, 0, 0, 0);
    }
    __builtin_amdgcn_s_setprio(0);

    if (!(kv0 + 63 <= qb)) {
#pragma unroll
      for (int r = 0; r < 16; ++r) {
        int kp = kv0 + (r & 3) + 8 * (r >> 2) + 4 * hi;
        if (kp > qrow) st0[r] = -1e30f;
        if (kp + 32 > qrow) st1[r] = -1e30f;
      }
    }
    float mx = -1e30f;
#pragma unroll
    for (int r = 0; r < 16; ++r) mx = fmaxf(mx, fmaxf(st0[r], st1[r]));
    mx = fmaxf(mx, __shfl_xor(mx, 32));
    if (__any(mx > mrow + 8.0f)) {
      float mnew = fmaxf(mrow, mx);
      float corr = exp2f(mrow - mnew);
      lrow *= corr;
      acc0 *= corr; acc1 *= corr; acc2 *= corr; acc3 *= corr;
      mrow = mnew;
    }
    float ps = 0.0f;
#pragma unroll
    for (int r = 0; r < 16; ++r) {
      float p0 = exp2f(st0[r] - mrow);
      float p1 = exp2f(st1[r] - mrow);
      ps += p0 + p1;
      st0[r] = p0;
      st1[r] = p1;
    }
    ps += __shfl_xor(ps, 32);
    lrow += ps;

    uint32_t W0[8], W1[8];
#pragma unroll
    for (int m = 0; m < 8; ++m) {
      W0[m] = pkbf(st0[2 * m], st0[2 * m + 1]);
      W1[m] = pkbf(st1[2 * m], st1[2 * m + 1]);
    }

    const bool hib = (hi != 0);
#pragma unroll
    for (int ks = 0; ks < 4; ++ks) {
      const int j = 4 * (ks & 1);
      uint32_t wj0, wj1, wj2, wj3;
      if (ks < 2) { wj0 = W0[j]; wj1 = W0[j + 1]; wj2 = W0[j + 2]; wj3 = W0[j + 3]; }
      else        { wj0 = W1[j]; wj1 = W1[j + 1]; wj2 = W1[j + 2]; wj3 = W1[j + 3]; }
      uint32_t keepA = hib ? wj2 : wj0;
      uint32_t keepB = hib ? wj3 : wj1;
      uint32_t sendA = hib ? wj0 : wj2;
      uint32_t sendB = hib ? wj1 : wj3;
      uint32_t recvA = (uint32_t)__shfl_xor((int)sendA, 32);
      uint32_t recvB = (uint32_t)__shfl_xor((int)sendB, 32);
      union { uint32_t u[4]; bf16x8 v; } fr;
      fr.u[0] = hib ? recvA : keepA;
      fr.u[1] = hib ? recvB : keepB;
      fr.u[2] = hib ? keepA : recvA;
      fr.u[3] = hib ? keepB : recvB;
      const int cV = (ks * 32 + hi * 16) ^ ((q5 & 7) << 4);
      __builtin_amdgcn_s_setprio(1);
      bf16x8 v0 = *reinterpret_cast<const bf16x8*>(Vt + (0 * 32 + q5) * 128 + cV);
      acc0 = __builtin_amdgcn_mfma_f32_32x32x16_bf16(v0, fr.v, acc0, 0, 0, 0);
      bf16x8 v1 = *reinterpret_cast<const bf16x8*>(Vt + (1 * 32 + q5) * 128 + cV);
      acc1 = __builtin_amdgcn_mfma_f32_32x32x16_bf16(v1, fr.v, acc1, 0, 0, 0);
      bf16x8 v2 = *reinterpret_cast<const bf16x8*>(Vt + (2 * 32 + q5) * 128 + cV);
      acc2 = __builtin_amdgcn_mfma_f32_32x32x16_bf16(v2, fr.v, acc2, 0, 0, 0);
      bf16x8 v3 = *reinterpret_cast<const bf16x8*>(Vt + (3 * 32 + q5) * 128 + cV);
      acc3 = __builtin_amdgcn_mfma_f32_32x32x16_bf16(v3, fr.v, acc3, 0, 0, 0);
      __builtin_amdgcn_s_setprio(0);
    }
    cur ^= 1;
  }

  __syncthreads();
  {
    char* ob = (char*)lds + wave * 8192;
    float inv = 1.0f / lrow;
    const int swzE = (q5 & 15) << 4;
#pragma unroll
    for (int dt = 0; dt < 4; ++dt) {
      f32x16 a = dt == 0 ? acc0 : dt == 1 ? acc1 : dt == 2 ? acc2 : acc3;
#pragma unroll
      for (int t4 = 0; t4 < 4; ++t4) {
        uint2 wv;
        wv.x = pkbf(a[4 * t4] * inv, a[4 * t4 + 1] * inv);
        wv.y = pkbf(a[4 * t4 + 2] * inv, a[4 * t4 + 3] * inv);
        int d2 = (dt * 32 + 8 * t4 + 4 * hi) * 2;
        *reinterpret_cast<uint2*>(ob + q5 * 256 + (d2 ^ swzE)) = wv;
      }
    }
#pragma unroll
    for (int rr = 0; rr < 8; ++rr) {
      int idx = rr * 64 + lane;
      int q = idx >> 4;
      int cc = (idx & 15) * 16;
      bf16x8 o = *reinterpret_cast<const bf16x8*>(ob + q * 256 + (cc ^ ((q & 15) << 4)));
      *reinterpret_cast<bf16x8*>(&attn[(size_t)(qb + q) * ATT_N + h * HD + (cc >> 1)]) = o;
    }
  }
}

extern "C" void kernel_launch(void* const* d_in, const int* in_sizes, int n_in,
                              void* d_out, int out_size, void* d_ws, size_t ws_size,
                              hipStream_t stream) {
  const float* hs   = (const float*)d_in[0];
  const int*   pos  = (const int*)d_in[1];
  const float* wqkv = (const float*)d_in[2];
  const float* wo   = (const float*)d_in[3];
  const float* qw   = (const float*)d_in[4];
  const float* kw   = (const float*)d_in[5];
  float* out = (float*)d_out;

  char* p = (char*)d_ws;
  __bf16* hsb   = (__bf16*)p; p += (size_t)T_TOK * HID * 2;
  __bf16* wqkvT = (__bf16*)p; p += (size_t)QKV_N * HID * 2;
  __bf16* woT   = (__bf16*)p; p += (size_t)HID * QSZ * 2;
  __bf16* qkvb  = (__bf16*)p; p += (size_t)T_TOK * QKV_N * 2;
  __bf16* attnb = (__bf16*)p; p += (size_t)T_TOK * QSZ * 2;
  __bf16* vtb   = (__bf16*)p; p += (size_t)NKV * HD * T_TOK * 2;
  float*  ropet = (float*)p;  p += (size_t)T_TOK * HD * 4;

  cast_f32_bf16<<<(T_TOK * HID / 4) / 256, 256, 0, stream>>>(hs, hsb, T_TOK * HID / 4);
  transpose_cast<<<dim3(QKV_N / 64, HID / 64), 256, 0, stream>>>(wqkv, wqkvT, HID, QKV_N);
  transpose_cast<<<dim3(HID / 64, QSZ / 64), 256, 0, stream>>>(wo, woT, QSZ, HID);
  rope_table<<<T_TOK, 64, 0, stream>>>(pos, ropet);
  // QKV projection: grid flattened (N/128)*(M/128) = 40*16 = 640 (div by 8)
  gemm_db<0><<<(QKV_N / 128) * (T_TOK / 128), 256, 0, stream>>>(
      hsb, wqkvT, qkvb, T_TOK, QKV_N, HID, QKV_N / 128);
  norm_rope<<<dim3(T_TOK, NH + NKV), 128, 0, stream>>>(qkvb, ropet, qw, kw);
  v_transpose<<<dim3(T_TOK / 64, HD / 64, NKV), 256, 0, stream>>>(qkvb, vtb);
  flash_attn5<<<dim3(64, 8), 256, 0, stream>>>(qkvb, vtb, attnb);
  // O projection: grid (2048/128)*(2048/128) = 16*16 = 256 (div by 8)
  gemm_db<1><<<(HID / 128) * (T_TOK / 128), 256, 0, stream>>>(
      attnb, woT, out, T_TOK, HID, QSZ, HID / 128);
}

// Round 7
// 281.005 us; speedup vs baseline: 3.5244x; 1.0207x over previous
//
#include <hip/hip_runtime.h>
#include <hip/hip_bf16.h>

typedef __attribute__((ext_vector_type(8))) __bf16 bf16x8;
typedef __attribute__((ext_vector_type(4))) __bf16 bf16x4;
typedef __attribute__((ext_vector_type(4))) float f32x4;
typedef __attribute__((ext_vector_type(16))) float f32x16;

#define T_TOK 2048
#define NH 32
#define NKV 4
#define HD 128
#define HID 2048
#define QKV_N 5120   // (32 + 2*4) * 128
#define QSZ 4096     // 32*128
#define KOFF 4096
#define VOFF 4608
#define ATT_N 4096

#define GLOAD_LDS16(g, l)                                              \
  __builtin_amdgcn_global_load_lds(                                    \
      (const __attribute__((address_space(1))) void*)(g),              \
      (__attribute__((address_space(3))) void*)(l), 16, 0, 0)

// ---------------- cast fp32 -> bf16 (row-major, vectorized) ----------------
__global__ __launch_bounds__(256) void cast_f32_bf16(const float* __restrict__ in,
                                                     __bf16* __restrict__ out, int n4) {
  int i = blockIdx.x * 256 + threadIdx.x;
  if (i < n4) {
    float4 v = reinterpret_cast<const float4*>(in)[i];
    bf16x4 o;
    o[0] = (__bf16)v.x; o[1] = (__bf16)v.y; o[2] = (__bf16)v.z; o[3] = (__bf16)v.w;
    reinterpret_cast<bf16x4*>(out)[i] = o;
  }
}

// ------------- cast + transpose: in fp32 [R][C] -> out bf16 [C][R] ---------
__global__ __launch_bounds__(256) void transpose_cast(const float* __restrict__ in,
                                                      __bf16* __restrict__ out,
                                                      int R, int C) {
  __shared__ __attribute__((aligned(16))) __bf16 tile[64][72];  // [c][r]
  const int c0 = blockIdx.x * 64;
  const int r0 = blockIdx.y * 64;
  const int ca = (threadIdx.x & 15) * 4;
  const int ra = (threadIdx.x >> 4) * 4;
  float4 v[4];
#pragma unroll
  for (int i = 0; i < 4; ++i)
    v[i] = *reinterpret_cast<const float4*>(&in[(size_t)(r0 + ra + i) * C + c0 + ca]);
#pragma unroll
  for (int j = 0; j < 4; ++j) {
    bf16x4 o;
#pragma unroll
    for (int i = 0; i < 4; ++i) o[i] = (__bf16)(((const float*)&v[i])[j]);
    *reinterpret_cast<bf16x4*>(&tile[ca + j][ra]) = o;
  }
  __syncthreads();
#pragma unroll
  for (int i = 0; i < 2; ++i) {
    int c = i * 32 + (threadIdx.x >> 3);
    int r8 = (threadIdx.x & 7) * 8;
    bf16x8 o = *reinterpret_cast<const bf16x8*>(&tile[c][r8]);
    *reinterpret_cast<bf16x8*>(&out[(size_t)(c0 + c) * R + r0 + r8]) = o;
  }
}

// ---- transpose V section of qkv: [t][kvh*128+d] -> vt[kvh][d][t] (bf16) ----
__global__ __launch_bounds__(256) void v_transpose(const __bf16* __restrict__ qkv,
                                                   __bf16* __restrict__ vt) {
  __shared__ __bf16 tile[64][72];
  int t0 = blockIdx.x * 64;
  int d0 = blockIdx.y * 64;
  int kvh = blockIdx.z;
  int tx = threadIdx.x & 63;
  int ty = threadIdx.x >> 6;
#pragma unroll
  for (int i = 0; i < 64; i += 4)
    tile[ty + i][tx] = qkv[(size_t)(t0 + ty + i) * QKV_N + VOFF + kvh * HD + d0 + tx];
  __syncthreads();
#pragma unroll
  for (int i = 0; i < 64; i += 4)
    vt[((size_t)kvh * HD + d0 + ty + i) * T_TOK + t0 + tx] = tile[tx][ty + i];
}

// ====== GEMM, 2-phase minimum recipe: C[M][N] = A[M][K]*B^T ================
// 128x128 tile, BK=32, 3 rotating LDS buffers (48KB), ONE barrier per K-step,
// issue-early / wait-late counted vmcnt, setprio around MFMA cluster.
template <int OUTF32>
__global__ __launch_bounds__(256) void gemm_p3(const __bf16* __restrict__ A,
                                               const __bf16* __restrict__ B,
                                               void* __restrict__ Cp,
                                               int M, int N, int K, int nbx) {
  __shared__ __attribute__((aligned(16))) __bf16 As[3][128][32];
  __shared__ __attribute__((aligned(16))) __bf16 Bs[3][128][32];
  const int tid = threadIdx.x;
  const int lane = tid & 63;
  const int wave = tid >> 6;
  const int la = lane & 15;
  const int lb = lane >> 4;
  const int wr = (wave >> 1) * 64;
  const int wc = (wave & 1) * 64;

  // bijective XCD swizzle (grid size divisible by 8)
  const int nwg = gridDim.x;
  const int cpx = nwg >> 3;
  const int swz = ((int)blockIdx.x & 7) * cpx + ((int)blockIdx.x >> 3);
  const int bx = swz % nbx;
  const int by = swz / nbx;
  const int rowA0 = by * 128;
  const int rowB0 = bx * 128;

  const int srow = wave * 16 + (lane >> 2);
  const int scol = (lane & 3) * 8;
  const __bf16* Asrc0 = &A[(size_t)(rowA0 + srow) * K + scol];
  const __bf16* Asrc1 = &A[(size_t)(rowA0 + 64 + srow) * K + scol];
  const __bf16* Bsrc0 = &B[(size_t)(rowB0 + srow) * K + scol];
  const __bf16* Bsrc1 = &B[(size_t)(rowB0 + 64 + srow) * K + scol];

#define STAGEG(b, k0)                                            \
  do {                                                           \
    GLOAD_LDS16(Asrc0 + (k0), &As[b][wave * 16][0]);             \
    GLOAD_LDS16(Asrc1 + (k0), &As[b][64 + wave * 16][0]);        \
    GLOAD_LDS16(Bsrc0 + (k0), &Bs[b][wave * 16][0]);             \
    GLOAD_LDS16(Bsrc1 + (k0), &Bs[b][64 + wave * 16][0]);        \
  } while (0)

  f32x4 acc[4][4] = {};

  const int nt = K >> 5;   // >= 64 for our shapes
  STAGEG(0, 0);
  STAGEG(1, 32);
  asm volatile("s_waitcnt vmcnt(4)" ::: "memory");   // tile 0 landed
  __builtin_amdgcn_s_barrier();
  __builtin_amdgcn_sched_barrier(0);

  int cur = 0, stg = 2;
  for (int t = 0; t < nt; ++t) {
    if (t + 2 < nt) {
      STAGEG(stg, (t + 2) * 32);   // issue early; lands during this MFMA phase
    }

    bf16x8 af[4], bfr[4];
#pragma unroll
    for (int m = 0; m < 4; ++m)
      af[m] = *reinterpret_cast<const bf16x8*>(&As[cur][wr + m * 16 + la][lb * 8]);
#pragma unroll
    for (int n = 0; n < 4; ++n)
      bfr[n] = *reinterpret_cast<const bf16x8*>(&Bs[cur][wc + n * 16 + la][lb * 8]);
    __builtin_amdgcn_s_setprio(1);
#pragma unroll
    for (int m = 0; m < 4; ++m)
#pragma unroll
      for (int n = 0; n < 4; ++n)
        acc[m][n] = __builtin_amdgcn_mfma_f32_16x16x32_bf16(af[m], bfr[n], acc[m][n], 0, 0, 0);
    __builtin_amdgcn_s_setprio(0);

    const int rem = nt - 1 - t;
    if (rem >= 2) {
      asm volatile("s_waitcnt vmcnt(4)" ::: "memory");  // tile t+1 landed, t+2 in flight
    } else if (rem == 1) {
      asm volatile("s_waitcnt vmcnt(0)" ::: "memory");
    }
    if (rem) {
      __builtin_amdgcn_sched_barrier(0);
      __builtin_amdgcn_s_barrier();     // single barrier per K-step
      __builtin_amdgcn_sched_barrier(0);
    }
    cur = (cur == 2) ? 0 : cur + 1;
    stg = (stg == 2) ? 0 : stg + 1;
  }
#undef STAGEG

#pragma unroll
  for (int m = 0; m < 4; ++m) {
#pragma unroll
    for (int n = 0; n < 4; ++n) {
#pragma unroll
      for (int r = 0; r < 4; ++r) {
        int row = rowA0 + wr + m * 16 + lb * 4 + r;
        int col = rowB0 + wc + n * 16 + la;
        if (OUTF32)
          reinterpret_cast<float*>(Cp)[(size_t)row * N + col] = acc[m][n][r];
        else
          reinterpret_cast<__bf16*>(Cp)[(size_t)row * N + col] = (__bf16)acc[m][n][r];
      }
    }
  }
}

// ---------------- RoPE cos/sin table: tab[t][0..63]=cos, [64..127]=sin -----
__global__ __launch_bounds__(64) void rope_table(const int* __restrict__ positions,
                                                 float* __restrict__ tab) {
  const int t = blockIdx.x;
  const int d = threadIdx.x;
  float freq = exp2f(-(float)d * 0.20762050593046015f);
  float fr = (float)positions[t] * freq;
  float c, s;
  sincosf(fr, &s, &c);
  tab[t * 128 + d] = c;
  tab[t * 128 + 64 + d] = s;
}

// ------------- RMSNorm + RoPE in-place on q/k rows of qkv buffer -----------
__global__ __launch_bounds__(128) void norm_rope(__bf16* __restrict__ qkv,
                                                 const float* __restrict__ tab,
                                                 const float* __restrict__ qw,
                                                 const float* __restrict__ kw) {
  const int t = blockIdx.x;
  const int head = blockIdx.y;
  const bool is_q = head < NH;
  const int col = is_q ? head * HD : KOFF + (head - NH) * HD;
  __bf16* row = qkv + (size_t)t * QKV_N + col;
  const int d = threadIdx.x;
  float x = (float)row[d];
  float ss = x * x;
#pragma unroll
  for (int mm = 1; mm < 64; mm <<= 1) ss += __shfl_xor(ss, mm);
  __shared__ float red[2];
  __shared__ float yl[128];
  if ((d & 63) == 0) red[d >> 6] = ss;
  __syncthreads();
  float var = (red[0] + red[1]) * (1.0f / 128.0f);
  float sc = rsqrtf(var + 1e-6f);
  const float* wv = is_q ? qw : kw;
  yl[d] = x * sc * wv[d];
  __syncthreads();
  if (d < 64) {
    float x1 = yl[d], x2 = yl[d + 64];
    float c = tab[t * 128 + d];
    float sn = tab[t * 128 + 64 + d];
    row[d] = (__bf16)(x1 * c - x2 * sn);
    row[d + 64] = (__bf16)(x2 * c + x1 * sn);
  }
}

// ===== flash attention, swapped-QK^T 32x32 structure =====
// grid (8, 64): x = kvh*2+half (fast dim), y = qtile order (descending work)
// -> the 8 heaviest blocks dispatch first, globally work-descending.
__device__ __forceinline__ uint32_t pkbf(float a, float b) {
  union { __bf16 h; unsigned short u; } x, y;
  x.h = (__bf16)a;
  y.h = (__bf16)b;
  return (uint32_t)x.u | ((uint32_t)y.u << 16);
}

__global__ __launch_bounds__(256, 2) void flash_attn5(const __bf16* __restrict__ qkv,
                                                      const __bf16* __restrict__ vt,
                                                      __bf16* __restrict__ attn) {
  __shared__ __attribute__((aligned(16))) __bf16 lds[32768];

  const int tid = threadIdx.x;
  const int lane = tid & 63;
  const int wave = tid >> 6;     // 0..3
  const int q5 = lane & 31;
  const int hi = lane >> 5;
  const int yy = blockIdx.x;     // 0..7
  const int kvh = yy >> 1;
  const int h = kvh * 8 + (yy & 1) * 4 + wave;
  const __bf16* Kbase = qkv + KOFF + kvh * HD;
  const __bf16* Vbase = vt + (size_t)kvh * HD * T_TOK;

  const int qt = 63 - (int)blockIdx.y;
  const int qb = qt * 32;
  const int qrow = qb + q5;
  const int nt = (qb + 32 + 63) >> 6;

  const float qscale = 0.088388347648318447f * 1.4426950408889634f;

  bf16x8 qf[8];
  {
    const __bf16* Qp = qkv + (size_t)(qb + q5) * QKV_N + h * HD + hi * 8;
#pragma unroll
    for (int k0 = 0; k0 < 8; ++k0) {
      bf16x8 q = *reinterpret_cast<const bf16x8*>(Qp + k0 * 16);
#pragma unroll
      for (int j = 0; j < 8; ++j) q[j] = (__bf16)((float)q[j] * qscale);
      qf[k0] = q;
    }
  }

  const int kc = (lane & 15) * 16;
  const int vc = (lane & 7) * 16;

#define STAGE5(b, kv00)                                                         \
  do {                                                                          \
    __bf16* kdst = lds + (b) * 8192;                                            \
    __bf16* vdst = lds + 16384 + (b) * 8192;                                    \
    _Pragma("unroll")                                                           \
    for (int i = 0; i < 4; ++i) {                                               \
      int kr = wave * 16 + i * 4 + (lane >> 4);                                 \
      int ksc = (kc ^ ((kr & 15) << 4)) >> 1;                                   \
      GLOAD_LDS16(Kbase + (size_t)((kv00) + kr) * QKV_N + ksc,                  \
                  kdst + (wave * 16 + i * 4) * 128);                            \
      int vr = wave * 32 + i * 8 + (lane >> 3);                                 \
      int vsc = (vc ^ ((vr & 7) << 4)) >> 1;                                    \
      GLOAD_LDS16(Vbase + (size_t)vr * T_TOK + (kv00) + vsc,                    \
                  vdst + (wave * 32 + i * 8) * 64);                             \
    }                                                                           \
  } while (0)

  f32x16 acc0 = {}, acc1 = {}, acc2 = {}, acc3 = {};
  float mrow = -1e30f, lrow = 0.0f;

  STAGE5(0, 0);

  int cur = 0;
  for (int t = 0; t < nt; ++t) {
    const int kv0 = t * 64;
    __builtin_amdgcn_s_barrier();
    __builtin_amdgcn_sched_barrier(0);
    if (t + 1 < nt) {
      STAGE5(cur ^ 1, kv0 + 64);
      asm volatile("s_waitcnt vmcnt(8)" ::: "memory");
    } else {
      asm volatile("s_waitcnt vmcnt(0)" ::: "memory");
    }
    __builtin_amdgcn_s_barrier();
    __builtin_amdgcn_sched_barrier(0);

    const char* Kt = (const char*)(lds + cur * 8192);
    const char* Vt = (const char*)(lds + 16384 + cur * 8192);

    f32x16 st0 = {}, st1 = {};
    __builtin_amdgcn_s_setprio(1);
#pragma unroll
    for (int k0 = 0; k0 < 8; ++k0) {
      int cS = (k0 * 32 + hi * 16) ^ ((q5 & 15) << 4);
      bf16x8 a0 = *reinterpret_cast<const bf16x8*>(Kt + q5 * 256 + cS);
      bf16x8 a1 = *reinterpret_cast<const bf16x8*>(Kt + (32 + q5) * 256 + cS);
      st0 = __builtin_amdgcn_mfma_f32_32x32x16_bf16(a0, qf[k0], st0, 0, 0, 0);
      st1 = __builtin_amdgcn_mfma_f32_32x32x16_bf16(a1, qf[k0], st1, 0, 0, 0);
    }
    __builtin_amdgcn_s_setprio(0);

    if (!(kv0 + 63 <= qb)) {
#pragma unroll
      for (int r = 0; r < 16; ++r) {
        int kp = kv0 + (r & 3) + 8 * (r >> 2) + 4 * hi;
        if (kp > qrow) st0[r] = -1e30f;
        if (kp + 32 > qrow) st1[r] = -1e30f;
      }
    }
    float mx = -1e30f;
#pragma unroll
    for (int r = 0; r < 16; ++r) mx = fmaxf(mx, fmaxf(st0[r], st1[r]));
    mx = fmaxf(mx, __shfl_xor(mx, 32));
    if (__any(mx > mrow + 8.0f)) {
      float mnew = fmaxf(mrow, mx);
      float corr = exp2f(mrow - mnew);
      lrow *= corr;
      acc0 *= corr; acc1 *= corr; acc2 *= corr; acc3 *= corr;
      mrow = mnew;
    }
    float ps = 0.0f;
#pragma unroll
    for (int r = 0; r < 16; ++r) {
      float p0 = exp2f(st0[r] - mrow);
      float p1 = exp2f(st1[r] - mrow);
      ps += p0 + p1;
      st0[r] = p0;
      st1[r] = p1;
    }
    ps += __shfl_xor(ps, 32);
    lrow += ps;

    uint32_t W0[8], W1[8];
#pragma unroll
    for (int m = 0; m < 8; ++m) {
      W0[m] = pkbf(st0[2 * m], st0[2 * m + 1]);
      W1[m] = pkbf(st1[2 * m], st1[2 * m + 1]);
    }

    const bool hib = (hi != 0);
#pragma unroll
    for (int ks = 0; ks < 4; ++ks) {
      const int j = 4 * (ks & 1);
      uint32_t wj0, wj1, wj2, wj3;
      if (ks < 2) { wj0 = W0[j]; wj1 = W0[j + 1]; wj2 = W0[j + 2]; wj3 = W0[j + 3]; }
      else        { wj0 = W1[j]; wj1 = W1[j + 1]; wj2 = W1[j + 2]; wj3 = W1[j + 3]; }
      uint32_t keepA = hib ? wj2 : wj0;
      uint32_t keepB = hib ? wj3 : wj1;
      uint32_t sendA = hib ? wj0 : wj2;
      uint32_t sendB = hib ? wj1 : wj3;
      uint32_t recvA = (uint32_t)__shfl_xor((int)sendA, 32);
      uint32_t recvB = (uint32_t)__shfl_xor((int)sendB, 32);
      union { uint32_t u[4]; bf16x8 v; } fr;
      fr.u[0] = hib ? recvA : keepA;
      fr.u[1] = hib ? recvB : keepB;
      fr.u[2] = hib ? keepA : recvA;
      fr.u[3] = hib ? keepB : recvB;
      const int cV = (ks * 32 + hi * 16) ^ ((q5 & 7) << 4);
      __builtin_amdgcn_s_setprio(1);
      bf16x8 v0 = *reinterpret_cast<const bf16x8*>(Vt + (0 * 32 + q5) * 128 + cV);
      acc0 = __builtin_amdgcn_mfma_f32_32x32x16_bf16(v0, fr.v, acc0, 0, 0, 0);
      bf16x8 v1 = *reinterpret_cast<const bf16x8*>(Vt + (1 * 32 + q5) * 128 + cV);
      acc1 = __builtin_amdgcn_mfma_f32_32x32x16_bf16(v1, fr.v, acc1, 0, 0, 0);
      bf16x8 v2 = *reinterpret_cast<const bf16x8*>(Vt + (2 * 32 + q5) * 128 + cV);
      acc2 = __builtin_amdgcn_mfma_f32_32x32x16_bf16(v2, fr.v, acc2, 0, 0, 0);
      bf16x8 v3 = *reinterpret_cast<const bf16x8*>(Vt + (3 * 32 + q5) * 128 + cV);
      acc3 = __builtin_amdgcn_mfma_f32_32x32x16_bf16(v3, fr.v, acc3, 0, 0, 0);
      __builtin_amdgcn_s_setprio(0);
    }
    cur ^= 1;
  }

  __syncthreads();
  {
    char* ob = (char*)lds + wave * 8192;
    float inv = 1.0f / lrow;
    const int swzE = (q5 & 15) << 4;
#pragma unroll
    for (int dt = 0; dt < 4; ++dt) {
      f32x16 a = dt == 0 ? acc0 : dt == 1 ? acc1 : dt == 2 ? acc2 : acc3;
#pragma unroll
      for (int t4 = 0; t4 < 4; ++t4) {
        uint2 wv;
        wv.x = pkbf(a[4 * t4] * inv, a[4 * t4 + 1] * inv);
        wv.y = pkbf(a[4 * t4 + 2] * inv, a[4 * t4 + 3] * inv);
        int d2 = (dt * 32 + 8 * t4 + 4 * hi) * 2;
        *reinterpret_cast<uint2*>(ob + q5 * 256 + (d2 ^ swzE)) = wv;
      }
    }
#pragma unroll
    for (int rr = 0; rr < 8; ++rr) {
      int idx = rr * 64 + lane;
      int q = idx >> 4;
      int cc = (idx & 15) * 16;
      bf16x8 o = *reinterpret_cast<const bf16x8*>(ob + q * 256 + (cc ^ ((q & 15) << 4)));
      *reinterpret_cast<bf16x8*>(&attn[(size_t)(qb + q) * ATT_N + h * HD + (cc >> 1)]) = o;
    }
  }
}

extern "C" void kernel_launch(void* const* d_in, const int* in_sizes, int n_in,
                              void* d_out, int out_size, void* d_ws, size_t ws_size,
                              hipStream_t stream) {
  const float* hs   = (const float*)d_in[0];
  const int*   pos  = (const int*)d_in[1];
  const float* wqkv = (const float*)d_in[2];
  const float* wo   = (const float*)d_in[3];
  const float* qw   = (const float*)d_in[4];
  const float* kw   = (const float*)d_in[5];
  float* out = (float*)d_out;

  char* p = (char*)d_ws;
  __bf16* hsb   = (__bf16*)p; p += (size_t)T_TOK * HID * 2;
  __bf16* wqkvT = (__bf16*)p; p += (size_t)QKV_N * HID * 2;
  __bf16* woT   = (__bf16*)p; p += (size_t)HID * QSZ * 2;
  __bf16* qkvb  = (__bf16*)p; p += (size_t)T_TOK * QKV_N * 2;
  __bf16* attnb = (__bf16*)p; p += (size_t)T_TOK * QSZ * 2;
  __bf16* vtb   = (__bf16*)p; p += (size_t)NKV * HD * T_TOK * 2;
  float*  ropet = (float*)p;  p += (size_t)T_TOK * HD * 4;

  cast_f32_bf16<<<(T_TOK * HID / 4) / 256, 256, 0, stream>>>(hs, hsb, T_TOK * HID / 4);
  transpose_cast<<<dim3(QKV_N / 64, HID / 64), 256, 0, stream>>>(wqkv, wqkvT, HID, QKV_N);
  transpose_cast<<<dim3(HID / 64, QSZ / 64), 256, 0, stream>>>(wo, woT, QSZ, HID);
  rope_table<<<T_TOK, 64, 0, stream>>>(pos, ropet);
  // QKV projection: grid flattened 40*16 = 640 (div by 8)
  gemm_p3<0><<<(QKV_N / 128) * (T_TOK / 128), 256, 0, stream>>>(
      hsb, wqkvT, qkvb, T_TOK, QKV_N, HID, QKV_N / 128);
  norm_rope<<<dim3(T_TOK, NH + NKV), 128, 0, stream>>>(qkvb, ropet, qw, kw);
  v_transpose<<<dim3(T_TOK / 64, HD / 64, NKV), 256, 0, stream>>>(qkvb, vtb);
  flash_attn5<<<dim3(8, 64), 256, 0, stream>>>(qkvb, vtb, attnb);
  // O projection: grid 16*16 = 256 (div by 8)
  gemm_p3<1><<<(HID / 128) * (T_TOK / 128), 256, 0, stream>>>(
      attnb, woT, out, T_TOK, HID, QSZ, HID / 128);
}